// Round 4
// baseline (1454.627 us; speedup 1.0000x reference)
//
#include <hip/hip_runtime.h>

#define HH 128
static constexpr int kN0 = 100000;
static constexpr int kC1 = 10000;
static constexpr int kC2 = 1000;

// Contiguous bin layout for the 5 CSR segments:
// [bins0 (kN0) | bins1 (kC1) | bins2 (kC2) | binsP1 (kC1) | binsP2 (kC2)]
static constexpr int B0 = kN0;              // 100000
static constexpr int B1 = B0 + kC1;         // 110000
static constexpr int B2 = B1 + kC2;         // 111000
static constexpr int B3 = B2 + kC1;         // 121000
static constexpr int NTOT = B3 + kC2;       // 122000
// Bucket = bin >> 7 (128 bins per bucket)
static constexpr int NB = (NTOT + 127) / 128;  // 954

// ---------------- P1: bucket histogram (LDS-privatized, coalesced flush) ----------------
__global__ __launch_bounds__(256) void p1_kernel(const int* __restrict__ col0,
                                                 const int* __restrict__ col1,
                                                 const int* __restrict__ col2,
                                                 const int* __restrict__ cl1,
                                                 const int* __restrict__ cl2,
                                                 int E0, int E1, int E2,
                                                 int* __restrict__ bucketCnt) {
  __shared__ int h[NB];
  for (int i = threadIdx.x; i < NB; i += 256) h[i] = 0;
  __syncthreads();
  int T0 = E0, T1 = T0 + E1, T2 = T1 + E2, T3 = T2 + kN0, T4 = T3 + kC1;
  for (int g = blockIdx.x * 256 + threadIdx.x; g < T4; g += gridDim.x * 256) {
    int bin;
    if (g < T0)      bin = col0[g];
    else if (g < T1) bin = B0 + col1[g - T0];
    else if (g < T2) bin = B1 + col2[g - T1];
    else if (g < T3) bin = B2 + cl1[g - T2];
    else             bin = B3 + cl2[g - T3];
    atomicAdd(&h[bin >> 7], 1);
  }
  __syncthreads();
  for (int i = threadIdx.x; i < NB; i += 256) {
    int c = h[i];
    if (c) atomicAdd(&bucketCnt[i], c);
  }
}

// ---------------- P2: scan bucket counts -> bucketStart + cursor ----------------
__global__ __launch_bounds__(1024) void p2_kernel(const int* __restrict__ bucketCnt,
                                                  int* __restrict__ bucketStart,
                                                  int* __restrict__ cursor,
                                                  int* __restrict__ startsg, int T) {
  int t = threadIdx.x;
  int v = (t < NB) ? bucketCnt[t] : 0;
  int lane = t & 63, w = t >> 6;
  int incl = v;
  for (int o = 1; o < 64; o <<= 1) { int u = __shfl_up(incl, o); if (lane >= o) incl += u; }
  __shared__ int wt[16];
  if (lane == 63) wt[w] = incl;
  __syncthreads();
  if (t == 0) { int run = 0; for (int i = 0; i < 16; i++) { int c = wt[i]; wt[i] = run; run += c; } }
  __syncthreads();
  int ex = wt[w] + incl - v;
  if (t < NB) { bucketStart[t] = ex; cursor[t] = ex; }
  if (t == 0) { bucketStart[NB] = T; startsg[NTOT] = T; }
}

// ---------------- P3: partition items into bucket regions ----------------
// Per 4096-item block: LDS ranks + one coalesced global reservation per touched bucket.
__global__ __launch_bounds__(256) void p3_kernel(const int* __restrict__ col0,
                                                 const int* __restrict__ col1,
                                                 const int* __restrict__ col2,
                                                 const int* __restrict__ cl1,
                                                 const int* __restrict__ cl2,
                                                 const int* __restrict__ row0,
                                                 const int* __restrict__ row1,
                                                 const int* __restrict__ row2,
                                                 const float* __restrict__ ew1,
                                                 const float* __restrict__ ew2,
                                                 int E0, int E1, int E2,
                                                 int* __restrict__ cursor,
                                                 int* __restrict__ partKey,
                                                 int* __restrict__ partSrc,
                                                 float* __restrict__ partW) {
  __shared__ int h[NB];
  __shared__ int gbase[NB];
  for (int i = threadIdx.x; i < NB; i += 256) h[i] = 0;
  __syncthreads();
  int T0 = E0, T1 = T0 + E1, T2 = T1 + E2, T3 = T2 + kN0, T4 = T3 + kC1;
  int base = blockIdx.x * 4096;
  int bins[16], srcs[16], rk[16];
  float wv[16];
#pragma unroll
  for (int j = 0; j < 16; j++) {
    int g = base + threadIdx.x + j * 256;
    int bin = -1, src = 0; float w = 0.f;
    if (g < T4) {
      if (g < T0) { bin = col0[g]; src = row0[g]; }
      else if (g < T1) { int e = g - T0; bin = B0 + col1[e]; src = row1[e]; w = ew1[e]; }
      else if (g < T2) { int e = g - T1; bin = B1 + col2[e]; src = row2[e]; w = ew2[e]; }
      else if (g < T3) { int e = g - T2; bin = B2 + cl1[e]; src = e; }
      else             { int e = g - T3; bin = B3 + cl2[e]; src = e; }
    }
    bins[j] = bin; srcs[j] = src; wv[j] = w;
    rk[j] = (bin >= 0) ? atomicAdd(&h[bin >> 7], 1) : 0;
  }
  __syncthreads();
  for (int i = threadIdx.x; i < NB; i += 256) {
    int c = h[i];
    gbase[i] = c ? atomicAdd(&cursor[i], c) : 0;
  }
  __syncthreads();
#pragma unroll
  for (int j = 0; j < 16; j++) {
    if (bins[j] >= 0) {
      int slot = gbase[bins[j] >> 7] + rk[j];
      partKey[slot] = bins[j];
      partSrc[slot] = srcs[j];
      partW[slot] = wv[j];
    }
  }
}

// ---------------- P4: per-bucket bin sort -> startsg, rowS, ewSm ----------------
__global__ __launch_bounds__(256) void p4_kernel(const int* __restrict__ bucketStart,
                                                 const int* __restrict__ partKey,
                                                 const int* __restrict__ partSrc,
                                                 const float* __restrict__ partW,
                                                 int* __restrict__ startsg,
                                                 int* __restrict__ rowS,
                                                 float* __restrict__ ewSm) {
  int b = blockIdx.x;
  int binLo = b << 7;
  int binHi = binLo + 128; if (binHi > NTOT) binHi = NTOT;
  int base = bucketStart[b], nend = bucketStart[b + 1];
  __shared__ int h[128];
  __shared__ int cur[128];
  int t = threadIdx.x;
  if (t < 128) h[t] = 0;
  __syncthreads();
  for (int i = base + t; i < nend; i += 256) atomicAdd(&h[partKey[i] - binLo], 1);
  __syncthreads();
  if (t == 0) {
    int run = 0;
    for (int j = 0; j < binHi - binLo; j++) {
      cur[j] = run;
      startsg[binLo + j] = base + run;
      run += h[j];
    }
  }
  __syncthreads();
  for (int i = base + t; i < nend; i += 256) {
    int k = partKey[i];
    int src = partSrc[i];
    float w = partW[i];
    int r = atomicAdd(&cur[k - binLo], 1);
    int dst = base + r;
    rowS[dst] = src;
    if (k >= B0 && k < B2) ewSm[dst] = w;
  }
}

// ---------------- dinv + weighted degrees (CSR segment sums, coalesced) ----------------
__global__ void dinv_kernel(const int* __restrict__ startsg, const float* __restrict__ ewSm,
                            float* __restrict__ d0, float* __restrict__ d1w,
                            float* __restrict__ d1o, float* __restrict__ d2) {
  int t = blockIdx.x * 256 + threadIdx.x;
  if (t < kN0) {
    int c = startsg[t + 1] - startsg[t];
    d0[t] = c > 0 ? rsqrtf((float)c) : 0.f;
  }
  int wid = t >> 6, lane = t & 63;
  if (wid < kC1) {
    int s = startsg[B0 + wid], e = startsg[B0 + wid + 1];
    float a = 0.f;
    for (int k = s + lane; k < e; k += 64) a += ewSm[k];
    for (int o = 32; o > 0; o >>= 1) a += __shfl_down(a, o);
    if (lane == 0) {
      d1w[wid] = a > 0.f ? rsqrtf(a) : 0.f;
      int c = e - s;
      d1o[wid] = c > 0 ? rsqrtf((float)c) : 0.f;
    }
  } else if (wid < kC1 + kC2) {
    int w2 = wid - kC1;
    int s = startsg[B1 + w2], e = startsg[B1 + w2 + 1];
    float a = 0.f;
    for (int k = s + lane; k < e; k += 64) a += ewSm[k];
    for (int o = 32; o > 0; o >>= 1) a += __shfl_down(a, o);
    if (lane == 0) d2[w2] = a > 0.f ? rsqrtf(a) : 0.f;
  }
}

// ---------------- GEMM: Y = (X [+ Xadd[cl]]) @ W (+bias) ----------------
__global__ __launch_bounds__(256) void matmul_kernel(const float* __restrict__ X,
                                                     const float* __restrict__ Xadd,
                                                     const int* __restrict__ cl,
                                                     const float* __restrict__ W,
                                                     const float* __restrict__ bias,
                                                     float* __restrict__ Y, int N) {
  __shared__ float Ws[64 * 128];
  __shared__ float Xs[32 * 128];
  int t = threadIdx.x;
  int rbase = blockIdx.x * 32;
  const float4* X4 = (const float4*)X;
  float4* Xs4 = (float4*)Xs;
#pragma unroll
  for (int i = 0; i < 4; i++) {
    int idx = t + 256 * i;
    int fr = idx >> 5, fc = idx & 31;
    int row = rbase + fr; if (row >= N) row = N - 1;
    float4 v = X4[(size_t)row * 32 + fc];
    if (Xadd) {
      int c = cl[row];
      float4 u = ((const float4*)Xadd)[(size_t)c * 32 + fc];
      v.x += u.x; v.y += u.y; v.z += u.z; v.w += u.w;
    }
    Xs4[idx] = v;
  }
  float acc[4][4];
#pragma unroll
  for (int r = 0; r < 4; r++)
#pragma unroll
    for (int cc = 0; cc < 4; cc++) acc[r][cc] = 0.f;
  int c0 = (t & 31) * 4;
  int rl = (t >> 5) * 4;
  const float4* W4 = (const float4*)W;
  float4* Ws4 = (float4*)Ws;
  for (int half = 0; half < 2; half++) {
    __syncthreads();
#pragma unroll
    for (int i = 0; i < 8; i++) {
      int idx = t + 256 * i;
      Ws4[idx] = W4[half * 2048 + idx];
    }
    __syncthreads();
#pragma unroll 4
    for (int k = 0; k < 64; k++) {
      float4 w4 = *(const float4*)(Ws + k * 128 + c0);
      float xv[4];
#pragma unroll
      for (int r = 0; r < 4; r++) xv[r] = Xs[(rl + r) * 128 + half * 64 + k];
#pragma unroll
      for (int r = 0; r < 4; r++) {
        acc[r][0] = fmaf(xv[r], w4.x, acc[r][0]);
        acc[r][1] = fmaf(xv[r], w4.y, acc[r][1]);
        acc[r][2] = fmaf(xv[r], w4.z, acc[r][2]);
        acc[r][3] = fmaf(xv[r], w4.w, acc[r][3]);
      }
    }
  }
  float4 b4 = make_float4(0.f, 0.f, 0.f, 0.f);
  if (bias) b4 = *(const float4*)(bias + c0);
#pragma unroll
  for (int r = 0; r < 4; r++) {
    int row = rbase + rl + r;
    if (row < N) {
      float4 o;
      o.x = acc[r][0] + b4.x; o.y = acc[r][1] + b4.y;
      o.z = acc[r][2] + b4.z; o.w = acc[r][3] + b4.w;
      *(float4*)(Y + (size_t)row * 128 + c0) = o;
    }
  }
}

// ---------------- CSR aggregation ----------------
__global__ __launch_bounds__(256) void agg_kernel(const float* __restrict__ Hf,
                                                  float* __restrict__ out,
                                                  const int* __restrict__ starts,
                                                  const int* __restrict__ rowS,
                                                  const float* __restrict__ ewSm,
                                                  const float* __restrict__ dinv,
                                                  const float* __restrict__ bias,
                                                  int C, int relu) {
  int wid = (blockIdx.x * blockDim.x + threadIdx.x) >> 6;
  int lane = threadIdx.x & 63;
  if (wid >= C) return;
  int s = starts[wid], e = starts[wid + 1];
  float dc = dinv[wid];
  float ax = 0.f, ay = 0.f;
  for (int base = s; base < e; base += 64) {
    int n = e - base; if (n > 64) n = 64;
    int moff = base + (lane < n ? lane : 0);
    int r = rowS[moff];
    float w = dinv[r] * (ewSm ? ewSm[moff] : 1.f);
    for (int j = 0; j < n; j++) {
      int rr = __shfl(r, j);
      float ww = __shfl(w, j);
      const float2 v = *(const float2*)(Hf + (size_t)rr * 128 + lane * 2);
      ax = fmaf(ww, v.x, ax);
      ay = fmaf(ww, v.y, ay);
    }
  }
  float ox = ax * dc + bias[lane * 2];
  float oy = ay * dc + bias[lane * 2 + 1];
  if (relu) { ox = fmaxf(ox, 0.f); oy = fmaxf(oy, 0.f); }
  *(float2*)(out + (size_t)wid * 128 + lane * 2) = make_float2(ox, oy);
}

// ---------------- seg_mean pooling: one wave per cluster ----------------
__global__ __launch_bounds__(256) void pool_kernel(const float* __restrict__ src,
                                                   float* __restrict__ out,
                                                   const int* __restrict__ starts,
                                                   const int* __restrict__ rowS, int C) {
  int wid = (blockIdx.x * blockDim.x + threadIdx.x) >> 6;
  int lane = threadIdx.x & 63;
  if (wid >= C) return;
  int s = starts[wid], e = starts[wid + 1];
  float ax = 0.f, ay = 0.f;
  for (int m = s; m < e; m++) {
    int id = rowS[m];
    const float2 v = *(const float2*)(src + (size_t)id * 128 + lane * 2);
    ax += v.x; ay += v.y;
  }
  float inv = (e > s) ? 1.f / (float)(e - s) : 0.f;
  *(float2*)(out + (size_t)wid * 128 + lane * 2) = make_float2(ax * inv, ay * inv);
}

// ---------------- out[i] = a[i] + b[cl[i]] (rowwise, float4) ----------------
__global__ void addgather_kernel(const float* __restrict__ a, const float* __restrict__ b,
                                 const int* __restrict__ cl, float* __restrict__ out, int nrows) {
  int g = blockIdx.x * 256 + threadIdx.x;
  if (g >= nrows * 32) return;
  int rowi = g >> 5;
  int c = cl[rowi];
  float4 va = ((const float4*)a)[g];
  float4 vb = ((const float4*)b)[(size_t)c * 32 + (g & 31)];
  float4 o;
  o.x = va.x + vb.x; o.y = va.y + vb.y; o.z = va.z + vb.z; o.w = va.w + vb.w;
  ((float4*)out)[g] = o;
}

// ---------------- host ----------------

extern "C" void kernel_launch(void* const* d_in, const int* in_sizes, int n_in,
                              void* d_out, int out_size, void* d_ws, size_t ws_size,
                              hipStream_t stream) {
  const float* x     = (const float*)d_in[0];
  const float* W_pre = (const float*)d_in[1];
  const float* b_pre = (const float*)d_in[2];
  const float* W_u0  = (const float*)d_in[3];
  const float* b_u0  = (const float*)d_in[4];
  const float* W_u1  = (const float*)d_in[5];
  const float* b_u1  = (const float*)d_in[6];
  const float* W_u2  = (const float*)d_in[7];
  const float* b_u2  = (const float*)d_in[8];
  const float* W_d0  = (const float*)d_in[9];
  const float* b_d0  = (const float*)d_in[10];
  const float* W_d1  = (const float*)d_in[11];
  const float* b_d1  = (const float*)d_in[12];
  const int* row0 = (const int*)d_in[13];
  const int* col0 = (const int*)d_in[14];
  const int* row1 = (const int*)d_in[16];
  const int* col1 = (const int*)d_in[17];
  const float* ew1 = (const float*)d_in[18];
  const int* row2 = (const int*)d_in[19];
  const int* col2 = (const int*)d_in[20];
  const float* ew2 = (const float*)d_in[21];
  const int* cluster1 = (const int*)d_in[22];
  const int* cluster2 = (const int*)d_in[23];
  int E0 = in_sizes[13], E1 = in_sizes[16], E2 = in_sizes[19];
  float* out = (float*)d_out;
  int Ttot = E0 + E1 + E2 + kN0 + kC1;

  char* basep = (char*)d_ws;
  size_t off = 0;
  auto alloc = [&](size_t bytes) -> char* {
    char* p = basep + off;
    off = (off + bytes + 255) & ~(size_t)255;
    return p;
  };
  // zero-init: bucketCnt only (first allocation)
  int* bucketCnt = (int*)alloc((size_t)NB * 4);
  size_t zero_bytes = off;
  // persistent (live through whole pipeline)
  int* bucketStart = (int*)alloc((size_t)(NB + 1) * 4);
  int* cursor      = (int*)alloc((size_t)NB * 4);
  int* startsg     = (int*)alloc((size_t)(NTOT + 1) * 4);
  int* rowS  = (int*)alloc((size_t)Ttot * 4);
  float* ewS = (float*)alloc((size_t)(E1 + E2) * 4);
  float* ewSm = ewS - E0;  // indexed by global CSR position (seg1/seg2 region only)
  float* dinv0  = (float*)alloc((size_t)kN0 * 4);
  float* dinv1w = (float*)alloc((size_t)kC1 * 4);
  float* dinv1o = (float*)alloc((size_t)kC1 * 4);
  float* dinv2  = (float*)alloc((size_t)kC2 * 4);
  // --- overlay region: partition scratch (dead after p4) aliases compute buffers ---
  size_t watermark = off;
  int* partKey   = (int*)alloc((size_t)Ttot * 4);
  int* partSrc   = (int*)alloc((size_t)Ttot * 4);
  float* partW   = (float*)alloc((size_t)Ttot * 4);
  off = watermark;  // rewind: compute buffers alias partition scratch
  float* A   = (float*)alloc((size_t)kN0 * HH * 4);
  float* s1a = (float*)alloc((size_t)kC1 * HH * 4);
  float* s1b = (float*)alloc((size_t)kC1 * HH * 4);
  float* s1c = (float*)alloc((size_t)kC1 * HH * 4);
  float* s2a = (float*)alloc((size_t)kC2 * HH * 4);
  float* s2b = (float*)alloc((size_t)kC2 * HH * 4);

  hipMemsetAsync(d_ws, 0, zero_bytes, stream);

  auto cdiv = [](int a, int b) { return (a + b - 1) / b; };

  // CSR build: bucket sort (no random global atomics)
  p1_kernel<<<256, 256, 0, stream>>>(col0, col1, col2, cluster1, cluster2, E0, E1, E2, bucketCnt);
  p2_kernel<<<1, 1024, 0, stream>>>(bucketCnt, bucketStart, cursor, startsg, Ttot);
  p3_kernel<<<cdiv(Ttot, 4096), 256, 0, stream>>>(col0, col1, col2, cluster1, cluster2,
                                                  row0, row1, row2, ew1, ew2, E0, E1, E2,
                                                  cursor, partKey, partSrc, partW);
  p4_kernel<<<NB, 256, 0, stream>>>(bucketStart, partKey, partSrc, partW, startsg, rowS, ewSm);
  dinv_kernel<<<cdiv((kC1 + kC2) * 64, 256), 256, 0, stream>>>(startsg, ewSm, dinv0, dinv1w,
                                                               dinv1o, dinv2);

  // h = x@W_pre + b_pre -> A      (A aliases partition scratch; p4 is complete by now)
  matmul_kernel<<<cdiv(kN0, 32), 256, 0, stream>>>(x, nullptr, nullptr, W_pre, b_pre, A, kN0);
  // t = h@W_u0 -> out (scratch)
  matmul_kernel<<<cdiv(kN0, 32), 256, 0, stream>>>(A, nullptr, nullptr, W_u0, nullptr, out, kN0);
  // x0 = relu(agg0(t) + b_u0) -> A
  agg_kernel<<<cdiv(kN0, 4), 256, 0, stream>>>(out, A, startsg, rowS, nullptr,
                                               dinv0, b_u0, kN0, 1);
  // x1m = seg_mean(x0, cluster1) -> s1a
  pool_kernel<<<cdiv(kC1, 4), 256, 0, stream>>>(A, s1a, startsg + B2, rowS, kC1);
  matmul_kernel<<<cdiv(kC1, 32), 256, 0, stream>>>(s1a, nullptr, nullptr, W_u1, nullptr, s1b, kC1);
  // x1 = relu(agg1_w(t1) + b_u1) -> s1a
  agg_kernel<<<cdiv(kC1, 4), 256, 0, stream>>>(s1b, s1a, startsg + B0, rowS, ewSm,
                                               dinv1w, b_u1, kC1, 1);
  // x2m = seg_mean(x1, cluster2) -> s2a
  pool_kernel<<<cdiv(kC2, 4), 256, 0, stream>>>(s1a, s2a, startsg + B3, rowS, kC2);
  matmul_kernel<<<cdiv(kC2, 32), 256, 0, stream>>>(s2a, nullptr, nullptr, W_u2, nullptr, s2b, kC2);
  // x2 = relu(agg2_w(t2) + b_u2) -> s2a
  agg_kernel<<<cdiv(kC2, 4), 256, 0, stream>>>(s2b, s2a, startsg + B1, rowS, ewSm,
                                               dinv2, b_u2, kC2, 1);
  // fused: (x1 + x2[cluster2]) @ W_d1 -> s1c
  matmul_kernel<<<cdiv(kC1, 32), 256, 0, stream>>>(s1a, s2a, cluster2, W_d1, nullptr, s1c, kC1);
  // y1 = relu(agg1_ones(t) + b_d1) -> s1b
  agg_kernel<<<cdiv(kC1, 4), 256, 0, stream>>>(s1c, s1b, startsg + B0, rowS, nullptr,
                                               dinv1o, b_d1, kC1, 1);
  // y0 = x0 + y1[cluster1] -> out (scratch)
  addgather_kernel<<<cdiv(kN0 * 32, 256), 256, 0, stream>>>(A, s1b, cluster1, out, kN0);
  matmul_kernel<<<cdiv(kN0, 32), 256, 0, stream>>>(out, nullptr, nullptr, W_d0, nullptr, A, kN0);
  // final: out = agg0(t) + b_d0 (no relu)
  agg_kernel<<<cdiv(kN0, 4), 256, 0, stream>>>(A, out, startsg, rowS, nullptr,
                                               dinv0, b_d0, kN0, 0);
}

// Round 5
// 1200.019 us; speedup vs baseline: 1.2122x; 1.2122x over previous
//
#include <hip/hip_runtime.h>

#define HH 128
static constexpr int kN0 = 100000;
static constexpr int kC1 = 10000;
static constexpr int kC2 = 1000;

// Contiguous bin layout for the 5 CSR segments:
// [bins0 (kN0) | bins1 (kC1) | bins2 (kC2) | binsP1 (kC1) | binsP2 (kC2)]
static constexpr int B0 = kN0;              // 100000
static constexpr int B1 = B0 + kC1;         // 110000
static constexpr int B2 = B1 + kC2;         // 111000
static constexpr int B3 = B2 + kC1;         // 121000
static constexpr int NTOT = B3 + kC2;       // 122000

// Variable-width buckets, sized for ~uniform ITEM count (~1-2k items/bucket):
// L0: 128 bins/bkt, L1: 8, L2: 1, P1: 128, P2: 16
static constexpr int NB0 = (kN0 + 127) / 128;   // 782
static constexpr int NB1 = (kC1 + 7) / 8;       // 1250
static constexpr int NB2 = kC2;                 // 1000
static constexpr int NBP1 = (kC1 + 127) / 128;  // 79
static constexpr int NBP2 = (kC2 + 15) / 16;    // 63
static constexpr int Q0 = NB0;                  // 782
static constexpr int Q1 = Q0 + NB1;             // 2032
static constexpr int Q2 = Q1 + NB2;             // 3032
static constexpr int Q3 = Q2 + NBP1;            // 3111
static constexpr int NBK = Q3 + NBP2;           // 3174

__device__ __forceinline__ int bucket_of(int bin) {
  if (bin < B0) return bin >> 7;
  if (bin < B1) return Q0 + ((bin - B0) >> 3);
  if (bin < B2) return Q1 + (bin - B1);
  if (bin < B3) return Q2 + ((bin - B2) >> 7);
  return Q3 + ((bin - B3) >> 4);
}

// ---------------- P1: bucket histogram (LDS-privatized, coalesced flush) ----------------
__global__ __launch_bounds__(256) void p1_kernel(const int* __restrict__ col0,
                                                 const int* __restrict__ col1,
                                                 const int* __restrict__ col2,
                                                 const int* __restrict__ cl1,
                                                 const int* __restrict__ cl2,
                                                 int E0, int E1, int E2,
                                                 int* __restrict__ bucketCnt) {
  __shared__ int h[NBK];
  for (int i = threadIdx.x; i < NBK; i += 256) h[i] = 0;
  __syncthreads();
  int T0 = E0, T1 = T0 + E1, T2 = T1 + E2, T3 = T2 + kN0, T4 = T3 + kC1;
  for (int g = blockIdx.x * 256 + threadIdx.x; g < T4; g += gridDim.x * 256) {
    int bin;
    if (g < T0)      bin = col0[g];
    else if (g < T1) bin = B0 + col1[g - T0];
    else if (g < T2) bin = B1 + col2[g - T1];
    else if (g < T3) bin = B2 + cl1[g - T2];
    else             bin = B3 + cl2[g - T3];
    atomicAdd(&h[bucket_of(bin)], 1);
  }
  __syncthreads();
  for (int i = threadIdx.x; i < NBK; i += 256) {
    int c = h[i];
    if (c) atomicAdd(&bucketCnt[i], c);
  }
}

// ---------------- P2: scan bucket counts (4/thread) -> bucketStart + cursor -----------
__global__ __launch_bounds__(1024) void p2_kernel(const int* __restrict__ bucketCnt,
                                                  int* __restrict__ bucketStart,
                                                  int* __restrict__ cursor,
                                                  int* __restrict__ startsg, int T) {
  int t = threadIdx.x;
  int v[4]; int s = 0;
#pragma unroll
  for (int j = 0; j < 4; j++) {
    int i = t * 4 + j;
    v[j] = (i < NBK) ? bucketCnt[i] : 0;
    s += v[j];
  }
  int lane = t & 63, w = t >> 6;
  int incl = s;
  for (int o = 1; o < 64; o <<= 1) { int u = __shfl_up(incl, o); if (lane >= o) incl += u; }
  __shared__ int wt[16];
  if (lane == 63) wt[w] = incl;
  __syncthreads();
  if (t == 0) { int run = 0; for (int i = 0; i < 16; i++) { int c = wt[i]; wt[i] = run; run += c; } }
  __syncthreads();
  int ex = wt[w] + incl - s;  // exclusive prefix of this thread's 4 buckets
#pragma unroll
  for (int j = 0; j < 4; j++) {
    int i = t * 4 + j;
    if (i < NBK) { bucketStart[i] = ex; cursor[i] = ex; }
    ex += v[j];
  }
  if (t == 0) { bucketStart[NBK] = T; startsg[NTOT] = T; }
}

// ---------------- P3: partition items into bucket regions ----------------
__global__ __launch_bounds__(256) void p3_kernel(const int* __restrict__ col0,
                                                 const int* __restrict__ col1,
                                                 const int* __restrict__ col2,
                                                 const int* __restrict__ cl1,
                                                 const int* __restrict__ cl2,
                                                 const int* __restrict__ row0,
                                                 const int* __restrict__ row1,
                                                 const int* __restrict__ row2,
                                                 const float* __restrict__ ew1,
                                                 const float* __restrict__ ew2,
                                                 int E0, int E1, int E2,
                                                 int* __restrict__ cursor,
                                                 int* __restrict__ partKey,
                                                 int* __restrict__ partSrc,
                                                 float* __restrict__ partW) {
  __shared__ int h[NBK];
  __shared__ int gbase[NBK];
  for (int i = threadIdx.x; i < NBK; i += 256) h[i] = 0;
  __syncthreads();
  int T0 = E0, T1 = T0 + E1, T2 = T1 + E2, T3 = T2 + kN0, T4 = T3 + kC1;
  int base = blockIdx.x * 4096;
  int bins[16], srcs[16], rk[16];
  float wv[16];
#pragma unroll
  for (int j = 0; j < 16; j++) {
    int g = base + threadIdx.x + j * 256;
    int bin = -1, src = 0; float w = 0.f;
    if (g < T4) {
      if (g < T0) { bin = col0[g]; src = row0[g]; }
      else if (g < T1) { int e = g - T0; bin = B0 + col1[e]; src = row1[e]; w = ew1[e]; }
      else if (g < T2) { int e = g - T1; bin = B1 + col2[e]; src = row2[e]; w = ew2[e]; }
      else if (g < T3) { int e = g - T2; bin = B2 + cl1[e]; src = e; }
      else             { int e = g - T3; bin = B3 + cl2[e]; src = e; }
    }
    bins[j] = bin; srcs[j] = src; wv[j] = w;
    rk[j] = (bin >= 0) ? atomicAdd(&h[bucket_of(bin)], 1) : 0;
  }
  __syncthreads();
  for (int i = threadIdx.x; i < NBK; i += 256) {
    int c = h[i];
    gbase[i] = c ? atomicAdd(&cursor[i], c) : 0;
  }
  __syncthreads();
#pragma unroll
  for (int j = 0; j < 16; j++) {
    if (bins[j] >= 0) {
      int slot = gbase[bucket_of(bins[j])] + rk[j];
      partKey[slot] = bins[j];
      partSrc[slot] = srcs[j];
      partW[slot] = wv[j];
    }
  }
}

// ---------------- P4: per-bucket bin sort -> startsg, rowS, ewSm ----------------
__global__ __launch_bounds__(256) void p4_kernel(const int* __restrict__ bucketStart,
                                                 const int* __restrict__ partKey,
                                                 const int* __restrict__ partSrc,
                                                 const float* __restrict__ partW,
                                                 int* __restrict__ startsg,
                                                 int* __restrict__ rowS,
                                                 float* __restrict__ ewSm) {
  int b = blockIdx.x;
  int binLo, width;
  if (b < Q0)      { binLo = b << 7;                 width = 128; if (binLo + width > B0) width = B0 - binLo; }
  else if (b < Q1) { binLo = B0 + ((b - Q0) << 3);   width = 8; }
  else if (b < Q2) { binLo = B1 + (b - Q1);          width = 1; }
  else if (b < Q3) { binLo = B2 + ((b - Q2) << 7);   width = 128; if (binLo + width > B3) width = B3 - binLo; }
  else             { binLo = B3 + ((b - Q3) << 4);   width = 16; if (binLo + width > NTOT) width = NTOT - binLo; }
  int base = bucketStart[b], nend = bucketStart[b + 1];
  int t = threadIdx.x;

  if (width == 1) {
    // single bin: already sorted; pure coalesced copy
    if (t == 0) startsg[binLo] = base;
    bool isEw = (binLo >= B0 && binLo < B2);
    for (int i = base + t; i < nend; i += 256) {
      rowS[i] = partSrc[i];
      if (isEw) ewSm[i] = partW[i];
    }
    return;
  }

  __shared__ int h[128];
  __shared__ int cur[128];
  if (t < 128) h[t] = 0;
  __syncthreads();
  for (int i = base + t; i < nend; i += 256) atomicAdd(&h[partKey[i] - binLo], 1);
  __syncthreads();
  if (t == 0) {
    int run = 0;
    for (int j = 0; j < width; j++) {
      cur[j] = run;
      startsg[binLo + j] = base + run;
      run += h[j];
    }
  }
  __syncthreads();
  for (int i = base + t; i < nend; i += 256) {
    int k = partKey[i];
    int src = partSrc[i];
    float w = partW[i];
    int r = atomicAdd(&cur[k - binLo], 1);
    int dst = base + r;
    rowS[dst] = src;
    if (k >= B0 && k < B2) ewSm[dst] = w;
  }
}

// ---------------- dinv + weighted degrees (CSR segment sums, coalesced) ----------------
__global__ void dinv_kernel(const int* __restrict__ startsg, const float* __restrict__ ewSm,
                            float* __restrict__ d0, float* __restrict__ d1w,
                            float* __restrict__ d1o, float* __restrict__ d2) {
  int t = blockIdx.x * 256 + threadIdx.x;
  if (t < kN0) {
    int c = startsg[t + 1] - startsg[t];
    d0[t] = c > 0 ? rsqrtf((float)c) : 0.f;
  }
  int wid = t >> 6, lane = t & 63;
  if (wid < kC1) {
    int s = startsg[B0 + wid], e = startsg[B0 + wid + 1];
    float a = 0.f;
    for (int k = s + lane; k < e; k += 64) a += ewSm[k];
    for (int o = 32; o > 0; o >>= 1) a += __shfl_down(a, o);
    if (lane == 0) {
      d1w[wid] = a > 0.f ? rsqrtf(a) : 0.f;
      int c = e - s;
      d1o[wid] = c > 0 ? rsqrtf((float)c) : 0.f;
    }
  } else if (wid < kC1 + kC2) {
    int w2 = wid - kC1;
    int s = startsg[B1 + w2], e = startsg[B1 + w2 + 1];
    float a = 0.f;
    for (int k = s + lane; k < e; k += 64) a += ewSm[k];
    for (int o = 32; o > 0; o >>= 1) a += __shfl_down(a, o);
    if (lane == 0) d2[w2] = a > 0.f ? rsqrtf(a) : 0.f;
  }
}

// ---------------- GEMM: Y = (X [+ Xadd[cl]]) @ W (+bias) ----------------
__global__ __launch_bounds__(256) void matmul_kernel(const float* __restrict__ X,
                                                     const float* __restrict__ Xadd,
                                                     const int* __restrict__ cl,
                                                     const float* __restrict__ W,
                                                     const float* __restrict__ bias,
                                                     float* __restrict__ Y, int N) {
  __shared__ float Ws[64 * 128];
  __shared__ float Xs[32 * 128];
  int t = threadIdx.x;
  int rbase = blockIdx.x * 32;
  const float4* X4 = (const float4*)X;
  float4* Xs4 = (float4*)Xs;
#pragma unroll
  for (int i = 0; i < 4; i++) {
    int idx = t + 256 * i;
    int fr = idx >> 5, fc = idx & 31;
    int row = rbase + fr; if (row >= N) row = N - 1;
    float4 v = X4[(size_t)row * 32 + fc];
    if (Xadd) {
      int c = cl[row];
      float4 u = ((const float4*)Xadd)[(size_t)c * 32 + fc];
      v.x += u.x; v.y += u.y; v.z += u.z; v.w += u.w;
    }
    Xs4[idx] = v;
  }
  float acc[4][4];
#pragma unroll
  for (int r = 0; r < 4; r++)
#pragma unroll
    for (int cc = 0; cc < 4; cc++) acc[r][cc] = 0.f;
  int c0 = (t & 31) * 4;
  int rl = (t >> 5) * 4;
  const float4* W4 = (const float4*)W;
  float4* Ws4 = (float4*)Ws;
  for (int half = 0; half < 2; half++) {
    __syncthreads();
#pragma unroll
    for (int i = 0; i < 8; i++) {
      int idx = t + 256 * i;
      Ws4[idx] = W4[half * 2048 + idx];
    }
    __syncthreads();
#pragma unroll 4
    for (int k = 0; k < 64; k++) {
      float4 w4 = *(const float4*)(Ws + k * 128 + c0);
      float xv[4];
#pragma unroll
      for (int r = 0; r < 4; r++) xv[r] = Xs[(rl + r) * 128 + half * 64 + k];
#pragma unroll
      for (int r = 0; r < 4; r++) {
        acc[r][0] = fmaf(xv[r], w4.x, acc[r][0]);
        acc[r][1] = fmaf(xv[r], w4.y, acc[r][1]);
        acc[r][2] = fmaf(xv[r], w4.z, acc[r][2]);
        acc[r][3] = fmaf(xv[r], w4.w, acc[r][3]);
      }
    }
  }
  float4 b4 = make_float4(0.f, 0.f, 0.f, 0.f);
  if (bias) b4 = *(const float4*)(bias + c0);
#pragma unroll
  for (int r = 0; r < 4; r++) {
    int row = rbase + rl + r;
    if (row < N) {
      float4 o;
      o.x = acc[r][0] + b4.x; o.y = acc[r][1] + b4.y;
      o.z = acc[r][2] + b4.z; o.w = acc[r][3] + b4.w;
      *(float4*)(Y + (size_t)row * 128 + c0) = o;
    }
  }
}

// ---------------- CSR aggregation ----------------
__global__ __launch_bounds__(256) void agg_kernel(const float* __restrict__ Hf,
                                                  float* __restrict__ out,
                                                  const int* __restrict__ starts,
                                                  const int* __restrict__ rowS,
                                                  const float* __restrict__ ewSm,
                                                  const float* __restrict__ dinv,
                                                  const float* __restrict__ bias,
                                                  int C, int relu) {
  int wid = (blockIdx.x * blockDim.x + threadIdx.x) >> 6;
  int lane = threadIdx.x & 63;
  if (wid >= C) return;
  int s = starts[wid], e = starts[wid + 1];
  float dc = dinv[wid];
  float ax = 0.f, ay = 0.f;
  for (int base = s; base < e; base += 64) {
    int n = e - base; if (n > 64) n = 64;
    int moff = base + (lane < n ? lane : 0);
    int r = rowS[moff];
    float w = dinv[r] * (ewSm ? ewSm[moff] : 1.f);
    for (int j = 0; j < n; j++) {
      int rr = __shfl(r, j);
      float ww = __shfl(w, j);
      const float2 v = *(const float2*)(Hf + (size_t)rr * 128 + lane * 2);
      ax = fmaf(ww, v.x, ax);
      ay = fmaf(ww, v.y, ay);
    }
  }
  float ox = ax * dc + bias[lane * 2];
  float oy = ay * dc + bias[lane * 2 + 1];
  if (relu) { ox = fmaxf(ox, 0.f); oy = fmaxf(oy, 0.f); }
  *(float2*)(out + (size_t)wid * 128 + lane * 2) = make_float2(ox, oy);
}

// ---------------- seg_mean pooling: one wave per cluster ----------------
__global__ __launch_bounds__(256) void pool_kernel(const float* __restrict__ src,
                                                   float* __restrict__ out,
                                                   const int* __restrict__ starts,
                                                   const int* __restrict__ rowS, int C) {
  int wid = (blockIdx.x * blockDim.x + threadIdx.x) >> 6;
  int lane = threadIdx.x & 63;
  if (wid >= C) return;
  int s = starts[wid], e = starts[wid + 1];
  float ax = 0.f, ay = 0.f;
  for (int m = s; m < e; m++) {
    int id = rowS[m];
    const float2 v = *(const float2*)(src + (size_t)id * 128 + lane * 2);
    ax += v.x; ay += v.y;
  }
  float inv = (e > s) ? 1.f / (float)(e - s) : 0.f;
  *(float2*)(out + (size_t)wid * 128 + lane * 2) = make_float2(ax * inv, ay * inv);
}

// ---------------- out[i] = a[i] + b[cl[i]] (rowwise, float4) ----------------
__global__ void addgather_kernel(const float* __restrict__ a, const float* __restrict__ b,
                                 const int* __restrict__ cl, float* __restrict__ out, int nrows) {
  int g = blockIdx.x * 256 + threadIdx.x;
  if (g >= nrows * 32) return;
  int rowi = g >> 5;
  int c = cl[rowi];
  float4 va = ((const float4*)a)[g];
  float4 vb = ((const float4*)b)[(size_t)c * 32 + (g & 31)];
  float4 o;
  o.x = va.x + vb.x; o.y = va.y + vb.y; o.z = va.z + vb.z; o.w = va.w + vb.w;
  ((float4*)out)[g] = o;
}

// ---------------- host ----------------

extern "C" void kernel_launch(void* const* d_in, const int* in_sizes, int n_in,
                              void* d_out, int out_size, void* d_ws, size_t ws_size,
                              hipStream_t stream) {
  const float* x     = (const float*)d_in[0];
  const float* W_pre = (const float*)d_in[1];
  const float* b_pre = (const float*)d_in[2];
  const float* W_u0  = (const float*)d_in[3];
  const float* b_u0  = (const float*)d_in[4];
  const float* W_u1  = (const float*)d_in[5];
  const float* b_u1  = (const float*)d_in[6];
  const float* W_u2  = (const float*)d_in[7];
  const float* b_u2  = (const float*)d_in[8];
  const float* W_d0  = (const float*)d_in[9];
  const float* b_d0  = (const float*)d_in[10];
  const float* W_d1  = (const float*)d_in[11];
  const float* b_d1  = (const float*)d_in[12];
  const int* row0 = (const int*)d_in[13];
  const int* col0 = (const int*)d_in[14];
  const int* row1 = (const int*)d_in[16];
  const int* col1 = (const int*)d_in[17];
  const float* ew1 = (const float*)d_in[18];
  const int* row2 = (const int*)d_in[19];
  const int* col2 = (const int*)d_in[20];
  const float* ew2 = (const float*)d_in[21];
  const int* cluster1 = (const int*)d_in[22];
  const int* cluster2 = (const int*)d_in[23];
  int E0 = in_sizes[13], E1 = in_sizes[16], E2 = in_sizes[19];
  float* out = (float*)d_out;
  int Ttot = E0 + E1 + E2 + kN0 + kC1;

  char* basep = (char*)d_ws;
  size_t off = 0;
  auto alloc = [&](size_t bytes) -> char* {
    char* p = basep + off;
    off = (off + bytes + 255) & ~(size_t)255;
    return p;
  };
  // zero-init: bucketCnt only (first allocation)
  int* bucketCnt = (int*)alloc((size_t)NBK * 4);
  size_t zero_bytes = off;
  // persistent
  int* bucketStart = (int*)alloc((size_t)(NBK + 1) * 4);
  int* cursor      = (int*)alloc((size_t)NBK * 4);
  int* startsg     = (int*)alloc((size_t)(NTOT + 1) * 4);
  int* rowS  = (int*)alloc((size_t)Ttot * 4);
  float* ewS = (float*)alloc((size_t)(E1 + E2) * 4);
  float* ewSm = ewS - E0;  // indexed by global CSR position (seg1/seg2 region only)
  float* dinv0  = (float*)alloc((size_t)kN0 * 4);
  float* dinv1w = (float*)alloc((size_t)kC1 * 4);
  float* dinv1o = (float*)alloc((size_t)kC1 * 4);
  float* dinv2  = (float*)alloc((size_t)kC2 * 4);
  // --- overlay region: partition scratch (dead after p4) aliases compute buffers ---
  size_t watermark = off;
  int* partKey   = (int*)alloc((size_t)Ttot * 4);
  int* partSrc   = (int*)alloc((size_t)Ttot * 4);
  float* partW   = (float*)alloc((size_t)Ttot * 4);
  off = watermark;  // rewind: compute buffers alias partition scratch
  float* A   = (float*)alloc((size_t)kN0 * HH * 4);
  float* s1a = (float*)alloc((size_t)kC1 * HH * 4);
  float* s1b = (float*)alloc((size_t)kC1 * HH * 4);
  float* s1c = (float*)alloc((size_t)kC1 * HH * 4);
  float* s2a = (float*)alloc((size_t)kC2 * HH * 4);
  float* s2b = (float*)alloc((size_t)kC2 * HH * 4);

  hipMemsetAsync(d_ws, 0, zero_bytes, stream);

  auto cdiv = [](int a, int b) { return (a + b - 1) / b; };

  // CSR build: bucket sort with ~uniform items/bucket
  p1_kernel<<<256, 256, 0, stream>>>(col0, col1, col2, cluster1, cluster2, E0, E1, E2, bucketCnt);
  p2_kernel<<<1, 1024, 0, stream>>>(bucketCnt, bucketStart, cursor, startsg, Ttot);
  p3_kernel<<<cdiv(Ttot, 4096), 256, 0, stream>>>(col0, col1, col2, cluster1, cluster2,
                                                  row0, row1, row2, ew1, ew2, E0, E1, E2,
                                                  cursor, partKey, partSrc, partW);
  p4_kernel<<<NBK, 256, 0, stream>>>(bucketStart, partKey, partSrc, partW, startsg, rowS, ewSm);
  dinv_kernel<<<cdiv((kC1 + kC2) * 64, 256), 256, 0, stream>>>(startsg, ewSm, dinv0, dinv1w,
                                                               dinv1o, dinv2);

  // h = x@W_pre + b_pre -> A      (A aliases partition scratch; p4 complete by then)
  matmul_kernel<<<cdiv(kN0, 32), 256, 0, stream>>>(x, nullptr, nullptr, W_pre, b_pre, A, kN0);
  // t = h@W_u0 -> out (scratch)
  matmul_kernel<<<cdiv(kN0, 32), 256, 0, stream>>>(A, nullptr, nullptr, W_u0, nullptr, out, kN0);
  // x0 = relu(agg0(t) + b_u0) -> A
  agg_kernel<<<cdiv(kN0, 4), 256, 0, stream>>>(out, A, startsg, rowS, nullptr,
                                               dinv0, b_u0, kN0, 1);
  // x1m = seg_mean(x0, cluster1) -> s1a
  pool_kernel<<<cdiv(kC1, 4), 256, 0, stream>>>(A, s1a, startsg + B2, rowS, kC1);
  matmul_kernel<<<cdiv(kC1, 32), 256, 0, stream>>>(s1a, nullptr, nullptr, W_u1, nullptr, s1b, kC1);
  // x1 = relu(agg1_w(t1) + b_u1) -> s1a
  agg_kernel<<<cdiv(kC1, 4), 256, 0, stream>>>(s1b, s1a, startsg + B0, rowS, ewSm,
                                               dinv1w, b_u1, kC1, 1);
  // x2m = seg_mean(x1, cluster2) -> s2a
  pool_kernel<<<cdiv(kC2, 4), 256, 0, stream>>>(s1a, s2a, startsg + B3, rowS, kC2);
  matmul_kernel<<<cdiv(kC2, 32), 256, 0, stream>>>(s2a, nullptr, nullptr, W_u2, nullptr, s2b, kC2);
  // x2 = relu(agg2_w(t2) + b_u2) -> s2a
  agg_kernel<<<cdiv(kC2, 4), 256, 0, stream>>>(s2b, s2a, startsg + B1, rowS, ewSm,
                                               dinv2, b_u2, kC2, 1);
  // fused: (x1 + x2[cluster2]) @ W_d1 -> s1c
  matmul_kernel<<<cdiv(kC1, 32), 256, 0, stream>>>(s1a, s2a, cluster2, W_d1, nullptr, s1c, kC1);
  // y1 = relu(agg1_ones(t) + b_d1) -> s1b
  agg_kernel<<<cdiv(kC1, 4), 256, 0, stream>>>(s1c, s1b, startsg + B0, rowS, nullptr,
                                               dinv1o, b_d1, kC1, 1);
  // y0 = x0 + y1[cluster1] -> out (scratch)
  addgather_kernel<<<cdiv(kN0 * 32, 256), 256, 0, stream>>>(A, s1b, cluster1, out, kN0);
  matmul_kernel<<<cdiv(kN0, 32), 256, 0, stream>>>(out, nullptr, nullptr, W_d0, nullptr, A, kN0);
  // final: out = agg0(t) + b_d0 (no relu)
  agg_kernel<<<cdiv(kN0, 4), 256, 0, stream>>>(A, out, startsg, rowS, nullptr,
                                               dinv0, b_d0, kN0, 0);
}

// Round 6
// 927.642 us; speedup vs baseline: 1.5681x; 1.2936x over previous
//
#include <hip/hip_runtime.h>

#define HH 128
static constexpr int kN0 = 100000;
static constexpr int kC1 = 10000;
static constexpr int kC2 = 1000;

// Contiguous bin layout for the 5 CSR segments:
// [bins0 (kN0) | bins1 (kC1) | bins2 (kC2) | binsP1 (kC1) | binsP2 (kC2)]
static constexpr int B0 = kN0;              // 100000
static constexpr int B1 = B0 + kC1;         // 110000
static constexpr int B2 = B1 + kC2;         // 111000
static constexpr int B3 = B2 + kC1;         // 121000
static constexpr int NTOT = B3 + kC2;       // 122000

// Variable-width buckets, sized for ~uniform ITEM count (~1-2k items/bucket):
// L0: 128 bins/bkt, L1: 8, L2: 1, P1: 128, P2: 16
static constexpr int NB0 = (kN0 + 127) / 128;   // 782
static constexpr int NB1 = (kC1 + 7) / 8;       // 1250
static constexpr int NB2 = kC2;                 // 1000
static constexpr int NBP1 = (kC1 + 127) / 128;  // 79
static constexpr int NBP2 = (kC2 + 15) / 16;    // 63
static constexpr int Q0 = NB0;                  // 782
static constexpr int Q1 = Q0 + NB1;             // 2032
static constexpr int Q2 = Q1 + NB2;             // 3032
static constexpr int Q3 = Q2 + NBP1;            // 3111
static constexpr int NBK = Q3 + NBP2;           // 3174

__device__ __forceinline__ int bucket_of(int bin) {
  if (bin < B0) return bin >> 7;
  if (bin < B1) return Q0 + ((bin - B0) >> 3);
  if (bin < B2) return Q1 + (bin - B1);
  if (bin < B3) return Q2 + ((bin - B2) >> 7);
  return Q3 + ((bin - B3) >> 4);
}

// ---------------- P1: bucket histogram (LDS-privatized, coalesced flush) ----------------
__global__ __launch_bounds__(256) void p1_kernel(const int* __restrict__ col0,
                                                 const int* __restrict__ col1,
                                                 const int* __restrict__ col2,
                                                 const int* __restrict__ cl1,
                                                 const int* __restrict__ cl2,
                                                 int E0, int E1, int E2,
                                                 int* __restrict__ bucketCnt) {
  __shared__ int h[NBK];
  for (int i = threadIdx.x; i < NBK; i += 256) h[i] = 0;
  __syncthreads();
  int T0 = E0, T1 = T0 + E1, T2 = T1 + E2, T3 = T2 + kN0, T4 = T3 + kC1;
  for (int g = blockIdx.x * 256 + threadIdx.x; g < T4; g += gridDim.x * 256) {
    int bin;
    if (g < T0)      bin = col0[g];
    else if (g < T1) bin = B0 + col1[g - T0];
    else if (g < T2) bin = B1 + col2[g - T1];
    else if (g < T3) bin = B2 + cl1[g - T2];
    else             bin = B3 + cl2[g - T3];
    atomicAdd(&h[bucket_of(bin)], 1);
  }
  __syncthreads();
  for (int i = threadIdx.x; i < NBK; i += 256) {
    int c = h[i];
    if (c) atomicAdd(&bucketCnt[i], c);
  }
}

// ---------------- P2: scan bucket counts (4/thread) -> bucketStart + cursor -----------
__global__ __launch_bounds__(1024) void p2_kernel(const int* __restrict__ bucketCnt,
                                                  int* __restrict__ bucketStart,
                                                  int* __restrict__ cursor,
                                                  int* __restrict__ startsg, int T) {
  int t = threadIdx.x;
  int v[4]; int s = 0;
#pragma unroll
  for (int j = 0; j < 4; j++) {
    int i = t * 4 + j;
    v[j] = (i < NBK) ? bucketCnt[i] : 0;
    s += v[j];
  }
  int lane = t & 63, w = t >> 6;
  int incl = s;
  for (int o = 1; o < 64; o <<= 1) { int u = __shfl_up(incl, o); if (lane >= o) incl += u; }
  __shared__ int wt[16];
  if (lane == 63) wt[w] = incl;
  __syncthreads();
  if (t == 0) { int run = 0; for (int i = 0; i < 16; i++) { int c = wt[i]; wt[i] = run; run += c; } }
  __syncthreads();
  int ex = wt[w] + incl - s;  // exclusive prefix of this thread's 4 buckets
#pragma unroll
  for (int j = 0; j < 4; j++) {
    int i = t * 4 + j;
    if (i < NBK) { bucketStart[i] = ex; cursor[i] = ex; }
    ex += v[j];
  }
  if (t == 0) { bucketStart[NBK] = T; startsg[NTOT] = T; }
}

// ---------------- P3: partition items into bucket regions (packed int4 payload) --------
__global__ __launch_bounds__(256) void p3_kernel(const int* __restrict__ col0,
                                                 const int* __restrict__ col1,
                                                 const int* __restrict__ col2,
                                                 const int* __restrict__ cl1,
                                                 const int* __restrict__ cl2,
                                                 const int* __restrict__ row0,
                                                 const int* __restrict__ row1,
                                                 const int* __restrict__ row2,
                                                 const float* __restrict__ ew1,
                                                 const float* __restrict__ ew2,
                                                 int E0, int E1, int E2,
                                                 int* __restrict__ cursor,
                                                 int4* __restrict__ part) {
  __shared__ int h[NBK];
  __shared__ int gbase[NBK];
  for (int i = threadIdx.x; i < NBK; i += 256) h[i] = 0;
  __syncthreads();
  int T0 = E0, T1 = T0 + E1, T2 = T1 + E2, T3 = T2 + kN0, T4 = T3 + kC1;
  int base = blockIdx.x * 4096;
  int bins[16], srcs[16], rk[16];
  float wv[16];
#pragma unroll
  for (int j = 0; j < 16; j++) {
    int g = base + threadIdx.x + j * 256;
    int bin = -1, src = 0; float w = 0.f;
    if (g < T4) {
      if (g < T0) { bin = col0[g]; src = row0[g]; }
      else if (g < T1) { int e = g - T0; bin = B0 + col1[e]; src = row1[e]; w = ew1[e]; }
      else if (g < T2) { int e = g - T1; bin = B1 + col2[e]; src = row2[e]; w = ew2[e]; }
      else if (g < T3) { int e = g - T2; bin = B2 + cl1[e]; src = e; }
      else             { int e = g - T3; bin = B3 + cl2[e]; src = e; }
    }
    bins[j] = bin; srcs[j] = src; wv[j] = w;
    rk[j] = (bin >= 0) ? atomicAdd(&h[bucket_of(bin)], 1) : 0;
  }
  __syncthreads();
  for (int i = threadIdx.x; i < NBK; i += 256) {
    int c = h[i];
    gbase[i] = c ? atomicAdd(&cursor[i], c) : 0;
  }
  __syncthreads();
#pragma unroll
  for (int j = 0; j < 16; j++) {
    if (bins[j] >= 0) {
      int slot = gbase[bucket_of(bins[j])] + rk[j];
      part[slot] = make_int4(bins[j], srcs[j], __float_as_int(wv[j]), 0);
    }
  }
}

// ---------------- P4: per-bucket bin sort -> startsg, rowS, ewSm ----------------
__global__ __launch_bounds__(256) void p4_kernel(const int* __restrict__ bucketStart,
                                                 const int4* __restrict__ part,
                                                 int* __restrict__ startsg,
                                                 int* __restrict__ rowS,
                                                 float* __restrict__ ewSm) {
  int b = blockIdx.x;
  int binLo, width;
  if (b < Q0)      { binLo = b << 7;                 width = 128; if (binLo + width > B0) width = B0 - binLo; }
  else if (b < Q1) { binLo = B0 + ((b - Q0) << 3);   width = 8; }
  else if (b < Q2) { binLo = B1 + (b - Q1);          width = 1; }
  else if (b < Q3) { binLo = B2 + ((b - Q2) << 7);   width = 128; if (binLo + width > B3) width = B3 - binLo; }
  else             { binLo = B3 + ((b - Q3) << 4);   width = 16; if (binLo + width > NTOT) width = NTOT - binLo; }
  int base = bucketStart[b], nend = bucketStart[b + 1];
  int t = threadIdx.x;

  if (width == 1) {
    // single bin: already sorted; pure coalesced copy
    if (t == 0) startsg[binLo] = base;
    bool isEw = (binLo >= B0 && binLo < B2);
    for (int i = base + t; i < nend; i += 256) {
      int4 it = part[i];
      rowS[i] = it.y;
      if (isEw) ewSm[i] = __int_as_float(it.z);
    }
    return;
  }

  __shared__ int h[128];
  __shared__ int cur[128];
  if (t < 128) h[t] = 0;
  __syncthreads();
  for (int i = base + t; i < nend; i += 256) atomicAdd(&h[part[i].x - binLo], 1);
  __syncthreads();
  if (t == 0) {
    int run = 0;
    for (int j = 0; j < width; j++) {
      cur[j] = run;
      startsg[binLo + j] = base + run;
      run += h[j];
    }
  }
  __syncthreads();
  for (int i = base + t; i < nend; i += 256) {
    int4 it = part[i];
    int k = it.x;
    int r = atomicAdd(&cur[k - binLo], 1);
    int dst = base + r;
    rowS[dst] = it.y;
    if (k >= B0 && k < B2) ewSm[dst] = __int_as_float(it.z);
  }
}

// ---------------- dinv + weighted degrees (CSR segment sums, coalesced) ----------------
__global__ void dinv_kernel(const int* __restrict__ startsg, const float* __restrict__ ewSm,
                            float* __restrict__ d0, float* __restrict__ d1w,
                            float* __restrict__ d1o, float* __restrict__ d2) {
  int t = blockIdx.x * 256 + threadIdx.x;
  if (t < kN0) {
    int c = startsg[t + 1] - startsg[t];
    d0[t] = c > 0 ? rsqrtf((float)c) : 0.f;
  }
  int wid = t >> 6, lane = t & 63;
  if (wid < kC1) {
    int s = startsg[B0 + wid], e = startsg[B0 + wid + 1];
    float a = 0.f;
    for (int k = s + lane; k < e; k += 64) a += ewSm[k];
    for (int o = 32; o > 0; o >>= 1) a += __shfl_down(a, o);
    if (lane == 0) {
      d1w[wid] = a > 0.f ? rsqrtf(a) : 0.f;
      int c = e - s;
      d1o[wid] = c > 0 ? rsqrtf((float)c) : 0.f;
    }
  } else if (wid < kC1 + kC2) {
    int w2 = wid - kC1;
    int s = startsg[B1 + w2], e = startsg[B1 + w2 + 1];
    float a = 0.f;
    for (int k = s + lane; k < e; k += 64) a += ewSm[k];
    for (int o = 32; o > 0; o >>= 1) a += __shfl_down(a, o);
    if (lane == 0) d2[w2] = a > 0.f ? rsqrtf(a) : 0.f;
  }
}

// ---------------- GEMM: Y = (X [+ Xadd[cl]]) @ W (+bias) ----------------
__global__ __launch_bounds__(256) void matmul_kernel(const float* __restrict__ X,
                                                     const float* __restrict__ Xadd,
                                                     const int* __restrict__ cl,
                                                     const float* __restrict__ W,
                                                     const float* __restrict__ bias,
                                                     float* __restrict__ Y, int N) {
  __shared__ float Ws[64 * 128];
  __shared__ float Xs[32 * 128];
  int t = threadIdx.x;
  int rbase = blockIdx.x * 32;
  const float4* X4 = (const float4*)X;
  float4* Xs4 = (float4*)Xs;
#pragma unroll
  for (int i = 0; i < 4; i++) {
    int idx = t + 256 * i;
    int fr = idx >> 5, fc = idx & 31;
    int row = rbase + fr; if (row >= N) row = N - 1;
    float4 v = X4[(size_t)row * 32 + fc];
    if (Xadd) {
      int c = cl[row];
      float4 u = ((const float4*)Xadd)[(size_t)c * 32 + fc];
      v.x += u.x; v.y += u.y; v.z += u.z; v.w += u.w;
    }
    Xs4[idx] = v;
  }
  float acc[4][4];
#pragma unroll
  for (int r = 0; r < 4; r++)
#pragma unroll
    for (int cc = 0; cc < 4; cc++) acc[r][cc] = 0.f;
  int c0 = (t & 31) * 4;
  int rl = (t >> 5) * 4;
  const float4* W4 = (const float4*)W;
  float4* Ws4 = (float4*)Ws;
  for (int half = 0; half < 2; half++) {
    __syncthreads();
#pragma unroll
    for (int i = 0; i < 8; i++) {
      int idx = t + 256 * i;
      Ws4[idx] = W4[half * 2048 + idx];
    }
    __syncthreads();
#pragma unroll 4
    for (int k = 0; k < 64; k++) {
      float4 w4 = *(const float4*)(Ws + k * 128 + c0);
      float xv[4];
#pragma unroll
      for (int r = 0; r < 4; r++) xv[r] = Xs[(rl + r) * 128 + half * 64 + k];
#pragma unroll
      for (int r = 0; r < 4; r++) {
        acc[r][0] = fmaf(xv[r], w4.x, acc[r][0]);
        acc[r][1] = fmaf(xv[r], w4.y, acc[r][1]);
        acc[r][2] = fmaf(xv[r], w4.z, acc[r][2]);
        acc[r][3] = fmaf(xv[r], w4.w, acc[r][3]);
      }
    }
  }
  float4 b4 = make_float4(0.f, 0.f, 0.f, 0.f);
  if (bias) b4 = *(const float4*)(bias + c0);
#pragma unroll
  for (int r = 0; r < 4; r++) {
    int row = rbase + rl + r;
    if (row < N) {
      float4 o;
      o.x = acc[r][0] + b4.x; o.y = acc[r][1] + b4.y;
      o.z = acc[r][2] + b4.z; o.w = acc[r][3] + b4.w;
      *(float4*)(Y + (size_t)row * 128 + c0) = o;
    }
  }
}

// ---------------- CSR aggregation (gather loop unrolled x4 for MLP) ----------------
__global__ __launch_bounds__(256) void agg_kernel(const float* __restrict__ Hf,
                                                  float* __restrict__ out,
                                                  const int* __restrict__ starts,
                                                  const int* __restrict__ rowS,
                                                  const float* __restrict__ ewSm,
                                                  const float* __restrict__ dinv,
                                                  const float* __restrict__ bias,
                                                  int C, int relu) {
  int wid = (blockIdx.x * blockDim.x + threadIdx.x) >> 6;
  int lane = threadIdx.x & 63;
  if (wid >= C) return;
  int s = starts[wid], e = starts[wid + 1];
  float dc = dinv[wid];
  float ax0 = 0.f, ay0 = 0.f, ax1 = 0.f, ay1 = 0.f;
  for (int base = s; base < e; base += 64) {
    int n = e - base; if (n > 64) n = 64;
    int moff = base + (lane < n ? lane : 0);
    int r = rowS[moff];
    float w = dinv[r] * (ewSm ? ewSm[moff] : 1.f);
    int j = 0;
    for (; j + 3 < n; j += 4) {
      int rr0 = __shfl(r, j), rr1 = __shfl(r, j + 1);
      int rr2 = __shfl(r, j + 2), rr3 = __shfl(r, j + 3);
      float w0 = __shfl(w, j), w1 = __shfl(w, j + 1);
      float w2 = __shfl(w, j + 2), w3 = __shfl(w, j + 3);
      float2 v0 = *(const float2*)(Hf + (size_t)rr0 * 128 + lane * 2);
      float2 v1 = *(const float2*)(Hf + (size_t)rr1 * 128 + lane * 2);
      float2 v2 = *(const float2*)(Hf + (size_t)rr2 * 128 + lane * 2);
      float2 v3 = *(const float2*)(Hf + (size_t)rr3 * 128 + lane * 2);
      ax0 = fmaf(w0, v0.x, ax0); ay0 = fmaf(w0, v0.y, ay0);
      ax1 = fmaf(w1, v1.x, ax1); ay1 = fmaf(w1, v1.y, ay1);
      ax0 = fmaf(w2, v2.x, ax0); ay0 = fmaf(w2, v2.y, ay0);
      ax1 = fmaf(w3, v3.x, ax1); ay1 = fmaf(w3, v3.y, ay1);
    }
    for (; j < n; j++) {
      int rr = __shfl(r, j);
      float ww = __shfl(w, j);
      const float2 v = *(const float2*)(Hf + (size_t)rr * 128 + lane * 2);
      ax0 = fmaf(ww, v.x, ax0); ay0 = fmaf(ww, v.y, ay0);
    }
  }
  float ox = (ax0 + ax1) * dc + bias[lane * 2];
  float oy = (ay0 + ay1) * dc + bias[lane * 2 + 1];
  if (relu) { ox = fmaxf(ox, 0.f); oy = fmaxf(oy, 0.f); }
  *(float2*)(out + (size_t)wid * 128 + lane * 2) = make_float2(ox, oy);
}

// ---------------- seg_mean pooling (unrolled x4) ----------------
__global__ __launch_bounds__(256) void pool_kernel(const float* __restrict__ src,
                                                   float* __restrict__ out,
                                                   const int* __restrict__ starts,
                                                   const int* __restrict__ rowS, int C) {
  int wid = (blockIdx.x * blockDim.x + threadIdx.x) >> 6;
  int lane = threadIdx.x & 63;
  if (wid >= C) return;
  int s = starts[wid], e = starts[wid + 1];
  float ax0 = 0.f, ay0 = 0.f, ax1 = 0.f, ay1 = 0.f;
  int m = s;
  for (; m + 3 < e; m += 4) {
    int i0 = rowS[m], i1 = rowS[m + 1], i2 = rowS[m + 2], i3 = rowS[m + 3];
    float2 v0 = *(const float2*)(src + (size_t)i0 * 128 + lane * 2);
    float2 v1 = *(const float2*)(src + (size_t)i1 * 128 + lane * 2);
    float2 v2 = *(const float2*)(src + (size_t)i2 * 128 + lane * 2);
    float2 v3 = *(const float2*)(src + (size_t)i3 * 128 + lane * 2);
    ax0 += v0.x; ay0 += v0.y;
    ax1 += v1.x; ay1 += v1.y;
    ax0 += v2.x; ay0 += v2.y;
    ax1 += v3.x; ay1 += v3.y;
  }
  for (; m < e; m++) {
    int id = rowS[m];
    const float2 v = *(const float2*)(src + (size_t)id * 128 + lane * 2);
    ax0 += v.x; ay0 += v.y;
  }
  float inv = (e > s) ? 1.f / (float)(e - s) : 0.f;
  *(float2*)(out + (size_t)wid * 128 + lane * 2) =
      make_float2((ax0 + ax1) * inv, (ay0 + ay1) * inv);
}

// ---------------- out[i] = a[i] + b[cl[i]] (rowwise, float4) ----------------
__global__ void addgather_kernel(const float* __restrict__ a, const float* __restrict__ b,
                                 const int* __restrict__ cl, float* __restrict__ out, int nrows) {
  int g = blockIdx.x * 256 + threadIdx.x;
  if (g >= nrows * 32) return;
  int rowi = g >> 5;
  int c = cl[rowi];
  float4 va = ((const float4*)a)[g];
  float4 vb = ((const float4*)b)[(size_t)c * 32 + (g & 31)];
  float4 o;
  o.x = va.x + vb.x; o.y = va.y + vb.y; o.z = va.z + vb.z; o.w = va.w + vb.w;
  ((float4*)out)[g] = o;
}

// ---------------- host ----------------

extern "C" void kernel_launch(void* const* d_in, const int* in_sizes, int n_in,
                              void* d_out, int out_size, void* d_ws, size_t ws_size,
                              hipStream_t stream) {
  const float* x     = (const float*)d_in[0];
  const float* W_pre = (const float*)d_in[1];
  const float* b_pre = (const float*)d_in[2];
  const float* W_u0  = (const float*)d_in[3];
  const float* b_u0  = (const float*)d_in[4];
  const float* W_u1  = (const float*)d_in[5];
  const float* b_u1  = (const float*)d_in[6];
  const float* W_u2  = (const float*)d_in[7];
  const float* b_u2  = (const float*)d_in[8];
  const float* W_d0  = (const float*)d_in[9];
  const float* b_d0  = (const float*)d_in[10];
  const float* W_d1  = (const float*)d_in[11];
  const float* b_d1  = (const float*)d_in[12];
  const int* row0 = (const int*)d_in[13];
  const int* col0 = (const int*)d_in[14];
  const int* row1 = (const int*)d_in[16];
  const int* col1 = (const int*)d_in[17];
  const float* ew1 = (const float*)d_in[18];
  const int* row2 = (const int*)d_in[19];
  const int* col2 = (const int*)d_in[20];
  const float* ew2 = (const float*)d_in[21];
  const int* cluster1 = (const int*)d_in[22];
  const int* cluster2 = (const int*)d_in[23];
  int E0 = in_sizes[13], E1 = in_sizes[16], E2 = in_sizes[19];
  float* out = (float*)d_out;
  int Ttot = E0 + E1 + E2 + kN0 + kC1;

  char* basep = (char*)d_ws;
  size_t off = 0;
  auto alloc = [&](size_t bytes) -> char* {
    char* p = basep + off;
    off = (off + bytes + 255) & ~(size_t)255;
    return p;
  };
  // zero-init: bucketCnt only (first allocation)
  int* bucketCnt = (int*)alloc((size_t)NBK * 4);
  size_t zero_bytes = off;
  // persistent
  int* bucketStart = (int*)alloc((size_t)(NBK + 1) * 4);
  int* cursor      = (int*)alloc((size_t)NBK * 4);
  int* startsg     = (int*)alloc((size_t)(NTOT + 1) * 4);
  int* rowS  = (int*)alloc((size_t)Ttot * 4);
  float* ewS = (float*)alloc((size_t)(E1 + E2) * 4);
  float* ewSm = ewS - E0;  // indexed by global CSR position (seg1/seg2 region only)
  float* dinv0  = (float*)alloc((size_t)kN0 * 4);
  float* dinv1w = (float*)alloc((size_t)kC1 * 4);
  float* dinv1o = (float*)alloc((size_t)kC1 * 4);
  float* dinv2  = (float*)alloc((size_t)kC2 * 4);
  // --- overlay region: partition scratch (dead after p4) aliases compute buffers ---
  size_t watermark = off;
  int4* part = (int4*)alloc((size_t)Ttot * 16);
  off = watermark;  // rewind: compute buffers alias partition scratch
  float* A   = (float*)alloc((size_t)kN0 * HH * 4);
  float* s1a = (float*)alloc((size_t)kC1 * HH * 4);
  float* s1b = (float*)alloc((size_t)kC1 * HH * 4);
  float* s1c = (float*)alloc((size_t)kC1 * HH * 4);
  float* s2a = (float*)alloc((size_t)kC2 * HH * 4);
  float* s2b = (float*)alloc((size_t)kC2 * HH * 4);

  hipMemsetAsync(d_ws, 0, zero_bytes, stream);

  auto cdiv = [](int a, int b) { return (a + b - 1) / b; };

  // CSR build: bucket sort with ~uniform items/bucket
  p1_kernel<<<256, 256, 0, stream>>>(col0, col1, col2, cluster1, cluster2, E0, E1, E2, bucketCnt);
  p2_kernel<<<1, 1024, 0, stream>>>(bucketCnt, bucketStart, cursor, startsg, Ttot);
  p3_kernel<<<cdiv(Ttot, 4096), 256, 0, stream>>>(col0, col1, col2, cluster1, cluster2,
                                                  row0, row1, row2, ew1, ew2, E0, E1, E2,
                                                  cursor, part);
  p4_kernel<<<NBK, 256, 0, stream>>>(bucketStart, part, startsg, rowS, ewSm);
  dinv_kernel<<<cdiv((kC1 + kC2) * 64, 256), 256, 0, stream>>>(startsg, ewSm, dinv0, dinv1w,
                                                               dinv1o, dinv2);

  // h = x@W_pre + b_pre -> A      (A aliases partition scratch; p4 complete by then)
  matmul_kernel<<<cdiv(kN0, 32), 256, 0, stream>>>(x, nullptr, nullptr, W_pre, b_pre, A, kN0);
  // t = h@W_u0 -> out (scratch)
  matmul_kernel<<<cdiv(kN0, 32), 256, 0, stream>>>(A, nullptr, nullptr, W_u0, nullptr, out, kN0);
  // x0 = relu(agg0(t) + b_u0) -> A
  agg_kernel<<<cdiv(kN0, 4), 256, 0, stream>>>(out, A, startsg, rowS, nullptr,
                                               dinv0, b_u0, kN0, 1);
  // x1m = seg_mean(x0, cluster1) -> s1a
  pool_kernel<<<cdiv(kC1, 4), 256, 0, stream>>>(A, s1a, startsg + B2, rowS, kC1);
  matmul_kernel<<<cdiv(kC1, 32), 256, 0, stream>>>(s1a, nullptr, nullptr, W_u1, nullptr, s1b, kC1);
  // x1 = relu(agg1_w(t1) + b_u1) -> s1a
  agg_kernel<<<cdiv(kC1, 4), 256, 0, stream>>>(s1b, s1a, startsg + B0, rowS, ewSm,
                                               dinv1w, b_u1, kC1, 1);
  // x2m = seg_mean(x1, cluster2) -> s2a
  pool_kernel<<<cdiv(kC2, 4), 256, 0, stream>>>(s1a, s2a, startsg + B3, rowS, kC2);
  matmul_kernel<<<cdiv(kC2, 32), 256, 0, stream>>>(s2a, nullptr, nullptr, W_u2, nullptr, s2b, kC2);
  // x2 = relu(agg2_w(t2) + b_u2) -> s2a
  agg_kernel<<<cdiv(kC2, 4), 256, 0, stream>>>(s2b, s2a, startsg + B1, rowS, ewSm,
                                               dinv2, b_u2, kC2, 1);
  // fused: (x1 + x2[cluster2]) @ W_d1 -> s1c
  matmul_kernel<<<cdiv(kC1, 32), 256, 0, stream>>>(s1a, s2a, cluster2, W_d1, nullptr, s1c, kC1);
  // y1 = relu(agg1_ones(t) + b_d1) -> s1b
  agg_kernel<<<cdiv(kC1, 4), 256, 0, stream>>>(s1c, s1b, startsg + B0, rowS, nullptr,
                                               dinv1o, b_d1, kC1, 1);
  // y0 = x0 + y1[cluster1] -> out (scratch)
  addgather_kernel<<<cdiv(kN0 * 32, 256), 256, 0, stream>>>(A, s1b, cluster1, out, kN0);
  matmul_kernel<<<cdiv(kN0, 32), 256, 0, stream>>>(out, nullptr, nullptr, W_d0, nullptr, A, kN0);
  // final: out = agg0(t) + b_d0 (no relu)
  agg_kernel<<<cdiv(kN0, 4), 256, 0, stream>>>(A, out, startsg, rowS, nullptr,
                                               dinv0, b_d0, kN0, 0);
}

// Round 7
// 764.990 us; speedup vs baseline: 1.9015x; 1.2126x over previous
//
#include <hip/hip_runtime.h>

#define HH 128
static constexpr int kN0 = 100000;
static constexpr int kC1 = 10000;
static constexpr int kC2 = 1000;

// Contiguous bin layout for the 5 CSR segments:
// [bins0 (kN0) | bins1 (kC1) | bins2 (kC2) | binsP1 (kC1) | binsP2 (kC2)]
static constexpr int B0 = kN0;              // 100000
static constexpr int B1 = B0 + kC1;         // 110000
static constexpr int B2 = B1 + kC2;         // 111000
static constexpr int B3 = B2 + kC1;         // 121000
static constexpr int NTOT = B3 + kC2;       // 122000

// Variable-width buckets, ~uniform ITEM count:
static constexpr int NB0 = (kN0 + 127) / 128;   // 782
static constexpr int NB1 = (kC1 + 7) / 8;       // 1250
static constexpr int NB2 = kC2;                 // 1000
static constexpr int NBP1 = (kC1 + 127) / 128;  // 79
static constexpr int NBP2 = (kC2 + 15) / 16;    // 63
static constexpr int Q0 = NB0;                  // 782
static constexpr int Q1 = Q0 + NB1;             // 2032
static constexpr int Q2 = Q1 + NB2;             // 3032
static constexpr int Q3 = Q2 + NBP1;            // 3111
static constexpr int NBK = Q3 + NBP2;           // 3174

__device__ __forceinline__ int bucket_of(int bin) {
  if (bin < B0) return bin >> 7;
  if (bin < B1) return Q0 + ((bin - B0) >> 3);
  if (bin < B2) return Q1 + (bin - B1);
  if (bin < B3) return Q2 + ((bin - B2) >> 7);
  return Q3 + ((bin - B3) >> 4);
}

// bf16x2 helpers (low 16 = even feature, high 16 = odd feature)
__device__ __forceinline__ unsigned int f2_to_bf2(float a, float b) {
  unsigned int ua = __float_as_uint(a);
  unsigned int ub = __float_as_uint(b);
  ua = (ua + 0x7fffu + ((ua >> 16) & 1u)) >> 16;
  ub = (ub + 0x7fffu + ((ub >> 16) & 1u)) & 0xffff0000u;
  return ua | ub;
}

// ---------------- P1: bucket histogram ----------------
__global__ __launch_bounds__(256) void p1_kernel(const int* __restrict__ col0,
                                                 const int* __restrict__ col1,
                                                 const int* __restrict__ col2,
                                                 const int* __restrict__ cl1,
                                                 const int* __restrict__ cl2,
                                                 int E0, int E1, int E2,
                                                 int* __restrict__ bucketCnt) {
  __shared__ int h[NBK];
  for (int i = threadIdx.x; i < NBK; i += 256) h[i] = 0;
  __syncthreads();
  int T0 = E0, T1 = T0 + E1, T2 = T1 + E2, T3 = T2 + kN0, T4 = T3 + kC1;
  for (int g = blockIdx.x * 256 + threadIdx.x; g < T4; g += gridDim.x * 256) {
    int bin;
    if (g < T0)      bin = col0[g];
    else if (g < T1) bin = B0 + col1[g - T0];
    else if (g < T2) bin = B1 + col2[g - T1];
    else if (g < T3) bin = B2 + cl1[g - T2];
    else             bin = B3 + cl2[g - T3];
    atomicAdd(&h[bucket_of(bin)], 1);
  }
  __syncthreads();
  for (int i = threadIdx.x; i < NBK; i += 256) {
    int c = h[i];
    if (c) atomicAdd(&bucketCnt[i], c);
  }
}

// ---------------- P2: scan bucket counts ----------------
__global__ __launch_bounds__(1024) void p2_kernel(const int* __restrict__ bucketCnt,
                                                  int* __restrict__ bucketStart,
                                                  int* __restrict__ cursor,
                                                  int* __restrict__ startsg, int T) {
  int t = threadIdx.x;
  int v[4]; int s = 0;
#pragma unroll
  for (int j = 0; j < 4; j++) {
    int i = t * 4 + j;
    v[j] = (i < NBK) ? bucketCnt[i] : 0;
    s += v[j];
  }
  int lane = t & 63, w = t >> 6;
  int incl = s;
  for (int o = 1; o < 64; o <<= 1) { int u = __shfl_up(incl, o); if (lane >= o) incl += u; }
  __shared__ int wt[16];
  if (lane == 63) wt[w] = incl;
  __syncthreads();
  if (t == 0) { int run = 0; for (int i = 0; i < 16; i++) { int c = wt[i]; wt[i] = run; run += c; } }
  __syncthreads();
  int ex = wt[w] + incl - s;
#pragma unroll
  for (int j = 0; j < 4; j++) {
    int i = t * 4 + j;
    if (i < NBK) { bucketStart[i] = ex; cursor[i] = ex; }
    ex += v[j];
  }
  if (t == 0) { bucketStart[NBK] = T; startsg[NTOT] = T; }
}

// ---------------- P3: partition into buckets (int4 payload) ----------------
__global__ __launch_bounds__(256) void p3_kernel(const int* __restrict__ col0,
                                                 const int* __restrict__ col1,
                                                 const int* __restrict__ col2,
                                                 const int* __restrict__ cl1,
                                                 const int* __restrict__ cl2,
                                                 const int* __restrict__ row0,
                                                 const int* __restrict__ row1,
                                                 const int* __restrict__ row2,
                                                 const float* __restrict__ ew1,
                                                 const float* __restrict__ ew2,
                                                 int E0, int E1, int E2,
                                                 int* __restrict__ cursor,
                                                 int4* __restrict__ part) {
  __shared__ int h[NBK];
  __shared__ int gbase[NBK];
  for (int i = threadIdx.x; i < NBK; i += 256) h[i] = 0;
  __syncthreads();
  int T0 = E0, T1 = T0 + E1, T2 = T1 + E2, T3 = T2 + kN0, T4 = T3 + kC1;
  int base = blockIdx.x * 4096;
  int bins[16], srcs[16], rk[16];
  float wv[16];
#pragma unroll
  for (int j = 0; j < 16; j++) {
    int g = base + threadIdx.x + j * 256;
    int bin = -1, src = 0; float w = 0.f;
    if (g < T4) {
      if (g < T0) { bin = col0[g]; src = row0[g]; }
      else if (g < T1) { int e = g - T0; bin = B0 + col1[e]; src = row1[e]; w = ew1[e]; }
      else if (g < T2) { int e = g - T1; bin = B1 + col2[e]; src = row2[e]; w = ew2[e]; }
      else if (g < T3) { int e = g - T2; bin = B2 + cl1[e]; src = e; }
      else             { int e = g - T3; bin = B3 + cl2[e]; src = e; }
    }
    bins[j] = bin; srcs[j] = src; wv[j] = w;
    rk[j] = (bin >= 0) ? atomicAdd(&h[bucket_of(bin)], 1) : 0;
  }
  __syncthreads();
  for (int i = threadIdx.x; i < NBK; i += 256) {
    int c = h[i];
    gbase[i] = c ? atomicAdd(&cursor[i], c) : 0;
  }
  __syncthreads();
#pragma unroll
  for (int j = 0; j < 16; j++) {
    if (bins[j] >= 0) {
      int slot = gbase[bucket_of(bins[j])] + rk[j];
      part[slot] = make_int4(bins[j], srcs[j], __float_as_int(wv[j]), 0);
    }
  }
}

// ---------------- P4: per-bucket bin sort -> startsg, rowS, ewSm ----------------
__global__ __launch_bounds__(256) void p4_kernel(const int* __restrict__ bucketStart,
                                                 const int4* __restrict__ part,
                                                 int* __restrict__ startsg,
                                                 int* __restrict__ rowS,
                                                 float* __restrict__ ewSm) {
  int b = blockIdx.x;
  int binLo, width;
  if (b < Q0)      { binLo = b << 7;                 width = 128; if (binLo + width > B0) width = B0 - binLo; }
  else if (b < Q1) { binLo = B0 + ((b - Q0) << 3);   width = 8; }
  else if (b < Q2) { binLo = B1 + (b - Q1);          width = 1; }
  else if (b < Q3) { binLo = B2 + ((b - Q2) << 7);   width = 128; if (binLo + width > B3) width = B3 - binLo; }
  else             { binLo = B3 + ((b - Q3) << 4);   width = 16; if (binLo + width > NTOT) width = NTOT - binLo; }
  int base = bucketStart[b], nend = bucketStart[b + 1];
  int t = threadIdx.x;

  if (width == 1) {
    if (t == 0) startsg[binLo] = base;
    bool isEw = (binLo >= B0 && binLo < B2);
    for (int i = base + t; i < nend; i += 256) {
      int4 it = part[i];
      rowS[i] = it.y;
      if (isEw) ewSm[i] = __int_as_float(it.z);
    }
    return;
  }

  __shared__ int h[128];
  __shared__ int cur[128];
  if (t < 128) h[t] = 0;
  __syncthreads();
  for (int i = base + t; i < nend; i += 256) atomicAdd(&h[part[i].x - binLo], 1);
  __syncthreads();
  if (t == 0) {
    int run = 0;
    for (int j = 0; j < width; j++) {
      cur[j] = run;
      startsg[binLo + j] = base + run;
      run += h[j];
    }
  }
  __syncthreads();
  for (int i = base + t; i < nend; i += 256) {
    int4 it = part[i];
    int k = it.x;
    int r = atomicAdd(&cur[k - binLo], 1);
    int dst = base + r;
    rowS[dst] = it.y;
    if (k >= B0 && k < B2) ewSm[dst] = __int_as_float(it.z);
  }
}

// ---------------- dinv + weighted degrees ----------------
__global__ void dinv_kernel(const int* __restrict__ startsg, const float* __restrict__ ewSm,
                            float* __restrict__ d0, float* __restrict__ d1w,
                            float* __restrict__ d1o, float* __restrict__ d2) {
  int t = blockIdx.x * 256 + threadIdx.x;
  if (t < kN0) {
    int c = startsg[t + 1] - startsg[t];
    d0[t] = c > 0 ? rsqrtf((float)c) : 0.f;
  }
  int wid = t >> 6, lane = t & 63;
  if (wid < kC1) {
    int s = startsg[B0 + wid], e = startsg[B0 + wid + 1];
    float a = 0.f;
    for (int k = s + lane; k < e; k += 64) a += ewSm[k];
    for (int o = 32; o > 0; o >>= 1) a += __shfl_down(a, o);
    if (lane == 0) {
      d1w[wid] = a > 0.f ? rsqrtf(a) : 0.f;
      int c = e - s;
      d1o[wid] = c > 0 ? rsqrtf((float)c) : 0.f;
    }
  } else if (wid < kC1 + kC2) {
    int w2 = wid - kC1;
    int s = startsg[B1 + w2], e = startsg[B1 + w2 + 1];
    float a = 0.f;
    for (int k = s + lane; k < e; k += 64) a += ewSm[k];
    for (int o = 32; o > 0; o >>= 1) a += __shfl_down(a, o);
    if (lane == 0) d2[w2] = a > 0.f ? rsqrtf(a) : 0.f;
  }
}

// ---------------- per-edge weight precompute ----------------
// wAll[e] (global CSR pos): seg0 = dinv0[r]; seg1 = d1w[r]*ew; seg2 = d2[r]*ew
// w1om[e] (seg1 positions only) = d1o[r]
__global__ void wprep_kernel(const int* __restrict__ rowS, const float* __restrict__ ewSm,
                             const float* __restrict__ dinv0, const float* __restrict__ d1w,
                             const float* __restrict__ d1o, const float* __restrict__ d2,
                             int E0, int E1, int E2,
                             float* __restrict__ wAll, float* __restrict__ w1om) {
  int e = blockIdx.x * 256 + threadIdx.x;
  int tot = E0 + E1 + E2;
  if (e >= tot) return;
  int r = rowS[e];
  if (e < E0) {
    wAll[e] = dinv0[r];
  } else if (e < E0 + E1) {
    wAll[e] = d1w[r] * ewSm[e];
    w1om[e] = d1o[r];
  } else {
    wAll[e] = d2[r] * ewSm[e];
  }
}

// ---------------- GEMM: Y = (X [+ Xadd[cl]]) @ W (+bias); f32 or bf16 output ----------
__global__ __launch_bounds__(256) void matmul_kernel(const float* __restrict__ X,
                                                     const float* __restrict__ Xadd,
                                                     const int* __restrict__ cl,
                                                     const float* __restrict__ W,
                                                     const float* __restrict__ bias,
                                                     float* __restrict__ Y,
                                                     unsigned int* __restrict__ Ybf, int N) {
  __shared__ float Ws[64 * 128];
  __shared__ float Xs[32 * 128];
  int t = threadIdx.x;
  int rbase = blockIdx.x * 32;
  const float4* X4 = (const float4*)X;
  float4* Xs4 = (float4*)Xs;
#pragma unroll
  for (int i = 0; i < 4; i++) {
    int idx = t + 256 * i;
    int fr = idx >> 5, fc = idx & 31;
    int row = rbase + fr; if (row >= N) row = N - 1;
    float4 v = X4[(size_t)row * 32 + fc];
    if (Xadd) {
      int c = cl[row];
      float4 u = ((const float4*)Xadd)[(size_t)c * 32 + fc];
      v.x += u.x; v.y += u.y; v.z += u.z; v.w += u.w;
    }
    Xs4[idx] = v;
  }
  float acc[4][4];
#pragma unroll
  for (int r = 0; r < 4; r++)
#pragma unroll
    for (int cc = 0; cc < 4; cc++) acc[r][cc] = 0.f;
  int c0 = (t & 31) * 4;
  int rl = (t >> 5) * 4;
  const float4* W4 = (const float4*)W;
  float4* Ws4 = (float4*)Ws;
  for (int half = 0; half < 2; half++) {
    __syncthreads();
#pragma unroll
    for (int i = 0; i < 8; i++) {
      int idx = t + 256 * i;
      Ws4[idx] = W4[half * 2048 + idx];
    }
    __syncthreads();
#pragma unroll 4
    for (int k = 0; k < 64; k++) {
      float4 w4 = *(const float4*)(Ws + k * 128 + c0);
      float xv[4];
#pragma unroll
      for (int r = 0; r < 4; r++) xv[r] = Xs[(rl + r) * 128 + half * 64 + k];
#pragma unroll
      for (int r = 0; r < 4; r++) {
        acc[r][0] = fmaf(xv[r], w4.x, acc[r][0]);
        acc[r][1] = fmaf(xv[r], w4.y, acc[r][1]);
        acc[r][2] = fmaf(xv[r], w4.z, acc[r][2]);
        acc[r][3] = fmaf(xv[r], w4.w, acc[r][3]);
      }
    }
  }
  float4 b4 = make_float4(0.f, 0.f, 0.f, 0.f);
  if (bias) b4 = *(const float4*)(bias + c0);
#pragma unroll
  for (int r = 0; r < 4; r++) {
    int row = rbase + rl + r;
    if (row < N) {
      float4 o;
      o.x = acc[r][0] + b4.x; o.y = acc[r][1] + b4.y;
      o.z = acc[r][2] + b4.z; o.w = acc[r][3] + b4.w;
      if (Ybf) {
        unsigned int pk0 = f2_to_bf2(o.x, o.y);
        unsigned int pk1 = f2_to_bf2(o.z, o.w);
        *(uint2*)(Ybf + (size_t)row * 64 + (c0 >> 1)) = make_uint2(pk0, pk1);
      } else {
        *(float4*)(Y + (size_t)row * 128 + c0) = o;
      }
    }
  }
}

// ---------------- CSR aggregation, wave per node, bf16 features ----------------
__global__ __launch_bounds__(256) void agg_kernel(const unsigned int* __restrict__ Hf,
                                                  float* __restrict__ out,
                                                  const int* __restrict__ starts,
                                                  const int* __restrict__ rowS,
                                                  const float* __restrict__ wS,
                                                  const float* __restrict__ dinv,
                                                  const float* __restrict__ bias,
                                                  int C, int relu) {
  int wid = (blockIdx.x * blockDim.x + threadIdx.x) >> 6;
  int lane = threadIdx.x & 63;
  if (wid >= C) return;
  int s = starts[wid], e = starts[wid + 1];
  float dc = dinv[wid];
  float ax[4] = {0.f, 0.f, 0.f, 0.f}, ay[4] = {0.f, 0.f, 0.f, 0.f};
  for (int base = s; base < e; base += 64) {
    int n = e - base; if (n > 64) n = 64;
    int moff = base + (lane < n ? lane : 0);
    int r = rowS[moff];
    float w = wS[moff];
    int j = 0;
    for (; j + 7 < n; j += 8) {
#pragma unroll
      for (int u = 0; u < 8; u++) {
        int rr = __shfl(r, j + u);
        float ww = __shfl(w, j + u);
        unsigned int pv = Hf[(size_t)rr * 64 + lane];
        ax[u & 3] = fmaf(ww, __uint_as_float(pv << 16), ax[u & 3]);
        ay[u & 3] = fmaf(ww, __uint_as_float(pv & 0xffff0000u), ay[u & 3]);
      }
    }
    for (; j < n; j++) {
      int rr = __shfl(r, j);
      float ww = __shfl(w, j);
      unsigned int pv = Hf[(size_t)rr * 64 + lane];
      ax[0] = fmaf(ww, __uint_as_float(pv << 16), ax[0]);
      ay[0] = fmaf(ww, __uint_as_float(pv & 0xffff0000u), ay[0]);
    }
  }
  float ox = (ax[0] + ax[1] + ax[2] + ax[3]) * dc + bias[lane * 2];
  float oy = (ay[0] + ay[1] + ay[2] + ay[3]) * dc + bias[lane * 2 + 1];
  if (relu) { ox = fmaxf(ox, 0.f); oy = fmaxf(oy, 0.f); }
  *(float2*)(out + (size_t)wid * 128 + lane * 2) = make_float2(ox, oy);
}

// ---------------- CSR aggregation, BLOCK per node (4 waves + LDS reduce) ----------------
__global__ __launch_bounds__(256) void aggb_kernel(const unsigned int* __restrict__ Hf,
                                                   float* __restrict__ out,
                                                   const int* __restrict__ starts,
                                                   const int* __restrict__ rowS,
                                                   const float* __restrict__ wS,
                                                   const float* __restrict__ dinv,
                                                   const float* __restrict__ bias,
                                                   int C, int relu) {
  int node = blockIdx.x;
  if (node >= C) return;
  int wv = threadIdx.x >> 6, lane = threadIdx.x & 63;
  int s = starts[node], e = starts[node + 1];
  float ax[4] = {0.f, 0.f, 0.f, 0.f}, ay[4] = {0.f, 0.f, 0.f, 0.f};
  for (int base = s + wv * 64; base < e; base += 256) {
    int n = e - base; if (n > 64) n = 64;
    int moff = base + (lane < n ? lane : 0);
    int r = rowS[moff];
    float w = wS[moff];
    int j = 0;
    for (; j + 7 < n; j += 8) {
#pragma unroll
      for (int u = 0; u < 8; u++) {
        int rr = __shfl(r, j + u);
        float ww = __shfl(w, j + u);
        unsigned int pv = Hf[(size_t)rr * 64 + lane];
        ax[u & 3] = fmaf(ww, __uint_as_float(pv << 16), ax[u & 3]);
        ay[u & 3] = fmaf(ww, __uint_as_float(pv & 0xffff0000u), ay[u & 3]);
      }
    }
    for (; j < n; j++) {
      int rr = __shfl(r, j);
      float ww = __shfl(w, j);
      unsigned int pv = Hf[(size_t)rr * 64 + lane];
      ax[0] = fmaf(ww, __uint_as_float(pv << 16), ax[0]);
      ay[0] = fmaf(ww, __uint_as_float(pv & 0xffff0000u), ay[0]);
    }
  }
  __shared__ float shx[256], shy[256];
  shx[threadIdx.x] = ax[0] + ax[1] + ax[2] + ax[3];
  shy[threadIdx.x] = ay[0] + ay[1] + ay[2] + ay[3];
  __syncthreads();
  if (threadIdx.x < 64) {
    float sx = shx[lane] + shx[lane + 64] + shx[lane + 128] + shx[lane + 192];
    float sy = shy[lane] + shy[lane + 64] + shy[lane + 128] + shy[lane + 192];
    float dc = dinv[node];
    float ox = sx * dc + bias[lane * 2];
    float oy = sy * dc + bias[lane * 2 + 1];
    if (relu) { ox = fmaxf(ox, 0.f); oy = fmaxf(oy, 0.f); }
    *(float2*)(out + (size_t)node * 128 + lane * 2) = make_float2(ox, oy);
  }
}

// ---------------- seg_mean pooling (unrolled x4, f32 src) ----------------
__global__ __launch_bounds__(256) void pool_kernel(const float* __restrict__ src,
                                                   float* __restrict__ out,
                                                   const int* __restrict__ starts,
                                                   const int* __restrict__ rowS, int C) {
  int wid = (blockIdx.x * blockDim.x + threadIdx.x) >> 6;
  int lane = threadIdx.x & 63;
  if (wid >= C) return;
  int s = starts[wid], e = starts[wid + 1];
  float ax0 = 0.f, ay0 = 0.f, ax1 = 0.f, ay1 = 0.f;
  int m = s;
  for (; m + 3 < e; m += 4) {
    int i0 = rowS[m], i1 = rowS[m + 1], i2 = rowS[m + 2], i3 = rowS[m + 3];
    float2 v0 = *(const float2*)(src + (size_t)i0 * 128 + lane * 2);
    float2 v1 = *(const float2*)(src + (size_t)i1 * 128 + lane * 2);
    float2 v2 = *(const float2*)(src + (size_t)i2 * 128 + lane * 2);
    float2 v3 = *(const float2*)(src + (size_t)i3 * 128 + lane * 2);
    ax0 += v0.x; ay0 += v0.y;
    ax1 += v1.x; ay1 += v1.y;
    ax0 += v2.x; ay0 += v2.y;
    ax1 += v3.x; ay1 += v3.y;
  }
  for (; m < e; m++) {
    int id = rowS[m];
    const float2 v = *(const float2*)(src + (size_t)id * 128 + lane * 2);
    ax0 += v.x; ay0 += v.y;
  }
  float inv = (e > s) ? 1.f / (float)(e - s) : 0.f;
  *(float2*)(out + (size_t)wid * 128 + lane * 2) =
      make_float2((ax0 + ax1) * inv, (ay0 + ay1) * inv);
}

// ---------------- out[i] = a[i] + b[cl[i]] (in-place capable, float4) ----------------
__global__ void addgather_kernel(const float* __restrict__ a, const float* __restrict__ b,
                                 const int* __restrict__ cl, float* __restrict__ out, int nrows) {
  int g = blockIdx.x * 256 + threadIdx.x;
  if (g >= nrows * 32) return;
  int rowi = g >> 5;
  int c = cl[rowi];
  float4 va = ((const float4*)a)[g];
  float4 vb = ((const float4*)b)[(size_t)c * 32 + (g & 31)];
  float4 o;
  o.x = va.x + vb.x; o.y = va.y + vb.y; o.z = va.z + vb.z; o.w = va.w + vb.w;
  ((float4*)out)[g] = o;
}

// ---------------- host ----------------

extern "C" void kernel_launch(void* const* d_in, const int* in_sizes, int n_in,
                              void* d_out, int out_size, void* d_ws, size_t ws_size,
                              hipStream_t stream) {
  const float* x     = (const float*)d_in[0];
  const float* W_pre = (const float*)d_in[1];
  const float* b_pre = (const float*)d_in[2];
  const float* W_u0  = (const float*)d_in[3];
  const float* b_u0  = (const float*)d_in[4];
  const float* W_u1  = (const float*)d_in[5];
  const float* b_u1  = (const float*)d_in[6];
  const float* W_u2  = (const float*)d_in[7];
  const float* b_u2  = (const float*)d_in[8];
  const float* W_d0  = (const float*)d_in[9];
  const float* b_d0  = (const float*)d_in[10];
  const float* W_d1  = (const float*)d_in[11];
  const float* b_d1  = (const float*)d_in[12];
  const int* row0 = (const int*)d_in[13];
  const int* col0 = (const int*)d_in[14];
  const int* row1 = (const int*)d_in[16];
  const int* col1 = (const int*)d_in[17];
  const float* ew1 = (const float*)d_in[18];
  const int* row2 = (const int*)d_in[19];
  const int* col2 = (const int*)d_in[20];
  const float* ew2 = (const float*)d_in[21];
  const int* cluster1 = (const int*)d_in[22];
  const int* cluster2 = (const int*)d_in[23];
  int E0 = in_sizes[13], E1 = in_sizes[16], E2 = in_sizes[19];
  float* out = (float*)d_out;
  int Ttot = E0 + E1 + E2 + kN0 + kC1;
  int Etot = E0 + E1 + E2;

  char* basep = (char*)d_ws;
  size_t off = 0;
  auto alloc = [&](size_t bytes) -> char* {
    char* p = basep + off;
    off = (off + bytes + 255) & ~(size_t)255;
    return p;
  };
  // zero-init: bucketCnt only
  int* bucketCnt = (int*)alloc((size_t)NBK * 4);
  size_t zero_bytes = off;
  // persistent
  int* bucketStart = (int*)alloc((size_t)(NBK + 1) * 4);
  int* cursor      = (int*)alloc((size_t)NBK * 4);
  int* startsg     = (int*)alloc((size_t)(NTOT + 1) * 4);
  int* rowS  = (int*)alloc((size_t)Ttot * 4);
  float* ewS = (float*)alloc((size_t)(E1 + E2) * 4);
  float* ewSm = ewS - E0;
  float* dinv0  = (float*)alloc((size_t)kN0 * 4);
  float* dinv1w = (float*)alloc((size_t)kC1 * 4);
  float* dinv1o = (float*)alloc((size_t)kC1 * 4);
  float* dinv2  = (float*)alloc((size_t)kC2 * 4);
  // --- overlay: part (dead after p4) aliases everything written after p4 ---
  size_t watermark = off;
  int4* part = (int4*)alloc((size_t)Ttot * 16);
  off = watermark;
  float* wAll = (float*)alloc((size_t)Etot * 4);
  float* w1o  = (float*)alloc((size_t)E1 * 4);
  float* w1om = w1o - E0;
  float* A    = (float*)alloc((size_t)kN0 * HH * 4);
  float* s1a  = (float*)alloc((size_t)kC1 * HH * 4);
  float* s1b  = (float*)alloc((size_t)kC1 * HH * 4);
  float* s2a  = (float*)alloc((size_t)kC2 * HH * 4);
  unsigned int* s1bb = (unsigned int*)alloc((size_t)kC1 * 64 * 4);
  unsigned int* s2bb = (unsigned int*)alloc((size_t)kC2 * 64 * 4);
  unsigned int* s1cb = (unsigned int*)alloc((size_t)kC1 * 64 * 4);
  unsigned int* tb   = (unsigned int*)alloc((size_t)kN0 * 64 * 4);
  unsigned int* t0   = (unsigned int*)d_out;  // bf16 scratch in d_out (dead before final write)

  hipMemsetAsync(d_ws, 0, zero_bytes, stream);

  auto cdiv = [](int a, int b) { return (a + b - 1) / b; };

  // CSR build
  p1_kernel<<<256, 256, 0, stream>>>(col0, col1, col2, cluster1, cluster2, E0, E1, E2, bucketCnt);
  p2_kernel<<<1, 1024, 0, stream>>>(bucketCnt, bucketStart, cursor, startsg, Ttot);
  p3_kernel<<<cdiv(Ttot, 4096), 256, 0, stream>>>(col0, col1, col2, cluster1, cluster2,
                                                  row0, row1, row2, ew1, ew2, E0, E1, E2,
                                                  cursor, part);
  p4_kernel<<<NBK, 256, 0, stream>>>(bucketStart, part, startsg, rowS, ewSm);
  dinv_kernel<<<cdiv((kC1 + kC2) * 64, 256), 256, 0, stream>>>(startsg, ewSm, dinv0, dinv1w,
                                                               dinv1o, dinv2);
  wprep_kernel<<<cdiv(Etot, 256), 256, 0, stream>>>(rowS, ewSm, dinv0, dinv1w, dinv1o, dinv2,
                                                    E0, E1, E2, wAll, w1om);

  // h = x@W_pre + b_pre -> A (f32)
  matmul_kernel<<<cdiv(kN0, 32), 256, 0, stream>>>(x, nullptr, nullptr, W_pre, b_pre, A, nullptr, kN0);
  // t0 = h@W_u0 -> bf16 (d_out scratch)
  matmul_kernel<<<cdiv(kN0, 32), 256, 0, stream>>>(A, nullptr, nullptr, W_u0, nullptr, nullptr, t0, kN0);
  // x0 = relu(agg0(t0) + b_u0) -> A
  agg_kernel<<<cdiv(kN0, 4), 256, 0, stream>>>(t0, A, startsg, rowS, wAll, dinv0, b_u0, kN0, 1);
  // x1m = seg_mean(x0, cluster1) -> s1a
  pool_kernel<<<cdiv(kC1, 4), 256, 0, stream>>>(A, s1a, startsg + B2, rowS, kC1);
  // t1 = x1m@W_u1 -> bf16 s1bb
  matmul_kernel<<<cdiv(kC1, 32), 256, 0, stream>>>(s1a, nullptr, nullptr, W_u1, nullptr, nullptr, s1bb, kC1);
  // x1 = relu(agg1_w(t1) + b_u1) -> s1a
  aggb_kernel<<<kC1, 256, 0, stream>>>(s1bb, s1a, startsg + B0, rowS, wAll, dinv1w, b_u1, kC1, 1);
  // x2m = seg_mean(x1, cluster2) -> s2a
  pool_kernel<<<cdiv(kC2, 4), 256, 0, stream>>>(s1a, s2a, startsg + B3, rowS, kC2);
  // t2 = x2m@W_u2 -> bf16 s2bb
  matmul_kernel<<<cdiv(kC2, 32), 256, 0, stream>>>(s2a, nullptr, nullptr, W_u2, nullptr, nullptr, s2bb, kC2);
  // x2 = relu(agg2_w(t2) + b_u2) -> s2a
  aggb_kernel<<<kC2, 256, 0, stream>>>(s2bb, s2a, startsg + B1, rowS, wAll, dinv2, b_u2, kC2, 1);
  // fused: (x1 + x2[cluster2]) @ W_d1 -> bf16 s1cb
  matmul_kernel<<<cdiv(kC1, 32), 256, 0, stream>>>(s1a, s2a, cluster2, W_d1, nullptr, nullptr, s1cb, kC1);
  // y1 = relu(agg1_ones(s1cb) + b_d1) -> s1b
  aggb_kernel<<<kC1, 256, 0, stream>>>(s1cb, s1b, startsg + B0, rowS, w1om, dinv1o, b_d1, kC1, 1);
  // y0 = x0 + y1[cluster1] -> A (in-place)
  addgather_kernel<<<cdiv(kN0 * 32, 256), 256, 0, stream>>>(A, s1b, cluster1, A, kN0);
  // t = y0@W_d0 -> bf16 tb
  matmul_kernel<<<cdiv(kN0, 32), 256, 0, stream>>>(A, nullptr, nullptr, W_d0, nullptr, nullptr, tb, kN0);
  // final: out = agg0(t) + b_d0 (no relu)
  agg_kernel<<<cdiv(kN0, 4), 256, 0, stream>>>(tb, out, startsg, rowS, wAll, dinv0, b_d0, kN0, 0);
}